// Round 11
// baseline (627.343 us; speedup 1.0000x reference)
//
#include <hip/hip_runtime.h>
#include <stdint.h>

#define BB 4
#define LL 2048
#define DMM 256
#define HH 8
#define EE 32
#define NLL 3
#define ITR 16
#define UU 40
#define ROWS (BB*LL)          // 8192
#define NELEM (ROWS*DMM)      // 2097152

typedef __attribute__((ext_vector_type(8))) short short8;
typedef __attribute__((ext_vector_type(4))) float f32x4;
typedef unsigned long long u64;

#define GLDS16(g, l)                                                        \
  __builtin_amdgcn_global_load_lds(                                         \
      (const __attribute__((address_space(1))) uint32_t*)(g),               \
      (__attribute__((address_space(3))) uint32_t*)(l), 16, 0, 0)

// ---------------- bf16 bit helpers (RNE) ----------------
__device__ __forceinline__ float bfbits(unsigned short u) {
  return __uint_as_float(((uint32_t)u) << 16);
}
__device__ __forceinline__ unsigned short f2b(float f) {
  uint32_t u = __float_as_uint(f);
  uint32_t r = (u + 0x7FFFu + ((u >> 16) & 1u)) >> 16;
  return (unsigned short)r;
}

// ---------------- threefry2x32 (exact JAX semantics) ----------------
__host__ __device__ inline void threefry2x32(uint32_t k0, uint32_t k1,
                                             uint32_t x0, uint32_t x1,
                                             uint32_t* o0, uint32_t* o1) {
  uint32_t ks2 = k0 ^ k1 ^ 0x1BD11BDAu;
  x0 += k0; x1 += k1;
#define TFR(r) { x0 += x1; x1 = (x1 << (r)) | (x1 >> (32 - (r))); x1 ^= x0; }
  TFR(13) TFR(15) TFR(26) TFR(6)
  x0 += k1;  x1 += ks2 + 1u;
  TFR(17) TFR(29) TFR(16) TFR(24)
  x0 += ks2; x1 += k0 + 2u;
  TFR(13) TFR(15) TFR(26) TFR(6)
  x0 += k0;  x1 += k1 + 3u;
  TFR(17) TFR(29) TFR(16) TFR(24)
  x0 += k1;  x1 += ks2 + 4u;
  TFR(13) TFR(15) TFR(26) TFR(6)
  x0 += ks2; x1 += k0 + 5u;
#undef TFR
  *o0 = x0; *o1 = x1;
}

__device__ __forceinline__ float wave_sum(float v) {
#pragma unroll
  for (int off = 32; off > 0; off >>= 1) v += __shfl_xor(v, off);
  return v;
}

// ---------------- dtype probe ----------------
__global__ __launch_bounds__(256) void probe_dtype(const void* __restrict__ x,
                                                   int* __restrict__ flag) {
  __shared__ int cnt;
  if (threadIdx.x == 0) cnt = 0;
  __syncthreads();
  const unsigned short* u = (const unsigned short*)x;
  int bad = 0;
  for (int j = threadIdx.x; j < 2048; j += 256) {
    float v = bfbits(u[j]);
    float a = fabsf(v);
    bool ok = (v == 0.0f) || (a > 1e-4f && a < 100.0f);
    if (!ok) bad++;
  }
  atomicAdd(&cnt, bad);
  __syncthreads();
  if (threadIdx.x == 0) *flag = (cnt > 100) ? 1 : 0;
}

// ---------------- mega convert (+hi/lo splits, +dcw repack, +zeroing) ----------------
struct CvtArgs {
  const void* src[23];
  float* dstF[23];
  unsigned short* dstB[23];
  unsigned short* dstL[23];
  int n[23];
  int blkStart[24];
  unsigned short* dcwT;
  float* vmpZ;     // zero BB*DMM floats
  int* cntZ;       // zero NLL*32 ints
};
__global__ __launch_bounds__(256) void mega_cvt(CvtArgs a, const int* __restrict__ flag) {
  int bid = blockIdx.x;
  if (bid == a.blkStart[23]) {
    for (int t = threadIdx.x; t < BB * DMM; t += 256) a.vmpZ[t] = 0.f;
    for (int t = threadIdx.x; t < NLL * 32; t += 256) a.cntZ[t] = 0;
    return;
  }
  int i = 0;
  while (i < 22 && bid >= a.blkStart[i + 1]) ++i;
  int e = (bid - a.blkStart[i]) * 256 + (int)threadIdx.x;
  if (e >= a.n[i]) return;
  float v; unsigned short rw;
  if (*flag) { v = ((const float*)a.src[i])[e]; rw = f2b(v); }
  else       { rw = ((const unsigned short*)a.src[i])[e]; v = bfbits(rw); }
  a.dstF[i][e] = v;
  if (a.dstB[i]) a.dstB[i][e] = rw;
  if (a.dstL[i]) a.dstL[i][e] = f2b(v - bfbits(rw));
  if (i == 17) {  // dcw: [ly][n][k][t] -> [ly][t][n][k] bf16
    int ly = e / 196608;
    int r = e - ly * 196608;
    int n = r / 768;
    int rem = r - n * 768;
    int k = rem / 3, t = rem - k * 3;
    a.dcwT[ly * 196608 + t * 65536 + n * 256 + k] = rw;
  }
}

// ---------------- QKV MFMA GEMM: z=0:Q 1:K (hi/lo 2-pass, f32 out) 2:V (bf16 out + vmean) --
struct QKVArgs {
  const unsigned short* W[3];
  const float* bias[3];
  float* Cq;
  float* Ck;
  unsigned short* Cv;
  float* vmp;
};
__global__ __launch_bounds__(256) void gemm_qkv(const unsigned short* __restrict__ Ahi,
                                                const unsigned short* __restrict__ Alo,
                                                QKVArgs qa) {
  __shared__ __attribute__((aligned(16))) unsigned short AsH[128][32];
  __shared__ __attribute__((aligned(16))) unsigned short AsL[128][32];
  __shared__ __attribute__((aligned(16))) unsigned short Bs[64][32];
  int z = blockIdx.z;
  const unsigned short* W = qa.W[z];
  const float* bias = qa.bias[z];
  bool twoPass = (z < 2);
  int bm = blockIdx.x * 128, bn = blockIdx.y * 64;
  int tid = threadIdx.x;
  int wv = tid >> 6, lane = tid & 63;
  int wm = wv >> 1, wn = wv & 1;
  int l15 = lane & 15, quad = lane >> 4;
  int lrow = lane >> 2, lseg = lane & 3;
  f32x4 acc[4][2];
#pragma unroll
  for (int i = 0; i < 4; ++i)
#pragma unroll
    for (int j = 0; j < 2; ++j) acc[i][j] = (f32x4){0.f, 0.f, 0.f, 0.f};
  for (int k0 = 0; k0 < 256; k0 += 32) {
    __syncthreads();
#pragma unroll
    for (int s = 0; s < 2; ++s) {
      int brow = (wv + s * 4) * 16;
      size_t goff = (size_t)(bm + brow + lrow) * 256 + k0 + lseg * 8;
      GLDS16(Ahi + goff, &AsH[brow][0]);
      if (twoPass) GLDS16(Alo + goff, &AsL[brow][0]);
    }
    {
      int brow = wv * 16;
      GLDS16(W + (size_t)(bn + brow + lrow) * 256 + k0 + lseg * 8, &Bs[brow][0]);
    }
    __syncthreads();
    short8 ah[4], bfr[2];
#pragma unroll
    for (int mt = 0; mt < 4; ++mt)
      ah[mt] = *(const short8*)(&AsH[wm * 64 + mt * 16 + l15][quad * 8]);
#pragma unroll
    for (int nt = 0; nt < 2; ++nt)
      bfr[nt] = *(const short8*)(&Bs[wn * 32 + nt * 16 + l15][quad * 8]);
#pragma unroll
    for (int mt = 0; mt < 4; ++mt)
#pragma unroll
      for (int nt = 0; nt < 2; ++nt)
        acc[mt][nt] = __builtin_amdgcn_mfma_f32_16x16x32_bf16(ah[mt], bfr[nt],
                                                              acc[mt][nt], 0, 0, 0);
    if (twoPass) {
      short8 al[4];
#pragma unroll
      for (int mt = 0; mt < 4; ++mt)
        al[mt] = *(const short8*)(&AsL[wm * 64 + mt * 16 + l15][quad * 8]);
#pragma unroll
      for (int mt = 0; mt < 4; ++mt)
#pragma unroll
        for (int nt = 0; nt < 2; ++nt)
          acc[mt][nt] = __builtin_amdgcn_mfma_f32_16x16x32_bf16(al[mt], bfr[nt],
                                                                acc[mt][nt], 0, 0, 0);
    }
  }
  float* C = (z == 0) ? qa.Cq : qa.Ck;
#pragma unroll
  for (int nt = 0; nt < 2; ++nt) {
    int n = bn + wn * 32 + nt * 16 + l15;
    float bv = bias[n];
    float csum = 0.f;
#pragma unroll
    for (int mt = 0; mt < 4; ++mt)
#pragma unroll
      for (int r = 0; r < 4; ++r) {
        int m = bm + wm * 64 + mt * 16 + quad * 4 + r;
        float val = acc[mt][nt][r] + bv;
        if (z < 2) {
          C[(size_t)m * 256 + n] = val;
        } else {
          qa.Cv[(size_t)m * 256 + n] = f2b(val);
          csum += val;
        }
      }
    if (z == 2) {
      csum += __shfl_xor(csum, 16);
      csum += __shfl_xor(csum, 32);
      if (quad == 0) {
        int b = bm >> 11;
        atomicAdd(&qa.vmp[b * DMM + n], csum);
      }
    }
  }
}

// ---------------- O-proj GEMM with on-the-fly ctx A-tiles ----------------
// A[row][k] = ctx value: selected row -> split-K merge of partials; else vmean.
__global__ __launch_bounds__(256) void gemm_oproj(const float* __restrict__ vmp,
                                                  const unsigned char* __restrict__ mapb,
                                                  const float* __restrict__ pm,
                                                  const float* __restrict__ pl,
                                                  const float* __restrict__ po,
                                                  const unsigned short* __restrict__ W,
                                                  const float* __restrict__ bias,
                                                  float* __restrict__ C) {
  __shared__ __attribute__((aligned(16))) unsigned short As[64][32];
  __shared__ __attribute__((aligned(16))) unsigned short Bs[64][32];
  int bm = blockIdx.x * 64, bn = blockIdx.y * 64;
  int tid = threadIdx.x;
  int wv = tid >> 6, lane = tid & 63;
  int wm = wv >> 1, wn = wv & 1;
  int l15 = lane & 15, quad = lane >> 4;
  int lrow = lane >> 2, lseg = lane & 3;
  int arow = tid >> 2, adg = tid & 3;   // A compute: row, 8-dim group
  int b = bm >> 11, l0 = bm & 2047;
  const float invL = 1.0f / (float)LL;
  f32x4 acc[2][2];
#pragma unroll
  for (int i = 0; i < 2; ++i)
#pragma unroll
    for (int j = 0; j < 2; ++j) acc[i][j] = (f32x4){0.f, 0.f, 0.f, 0.f};
  for (int k0 = 0; k0 < 256; k0 += 32) {
    int h = k0 >> 5;
    int bh = b * HH + h;
    __syncthreads();
    // compute A tile (ctx[bm..bm+64][k0..k0+32]) into LDS as bf16
    {
      int l = l0 + arow;
      int q = (int)mapb[bh * 2048 + l];
      unsigned short outv[8];
      if (q) {
        size_t base = ((size_t)bh * UU + (q - 1)) * 8;
        float Mx = -1e30f;
#pragma unroll
        for (int kc = 0; kc < 8; ++kc) Mx = fmaxf(Mx, pm[base + kc]);
        float Ls = 0.f;
        float sc[8];
#pragma unroll
        for (int kc = 0; kc < 8; ++kc) {
          sc[kc] = expf(pm[base + kc] - Mx);
          Ls += pl[base + kc] * sc[kc];
        }
        float inv = 1.0f / Ls;
#pragma unroll
        for (int j = 0; j < 8; ++j) {
          int dl = adg * 8 + j;
          float o = 0.f;
#pragma unroll
          for (int kc = 0; kc < 8; ++kc) o += po[(base + kc) * 32 + dl] * sc[kc];
          outv[j] = f2b(o * inv);
        }
      } else {
        const float* vp = vmp + b * DMM + h * EE + adg * 8;
#pragma unroll
        for (int j = 0; j < 8; ++j) outv[j] = f2b(vp[j] * invL);
      }
      *(uint4*)(&As[arow][adg * 8]) = *(const uint4*)outv;
    }
    {
      int brow = wv * 16;
      GLDS16(W + (size_t)(bn + brow + lrow) * 256 + k0 + lseg * 8, &Bs[brow][0]);
    }
    __syncthreads();
    short8 af[2], bfr[2];
#pragma unroll
    for (int mt = 0; mt < 2; ++mt)
      af[mt] = *(const short8*)(&As[wm * 32 + mt * 16 + l15][quad * 8]);
#pragma unroll
    for (int nt = 0; nt < 2; ++nt)
      bfr[nt] = *(const short8*)(&Bs[wn * 32 + nt * 16 + l15][quad * 8]);
#pragma unroll
    for (int mt = 0; mt < 2; ++mt)
#pragma unroll
      for (int nt = 0; nt < 2; ++nt)
        acc[mt][nt] = __builtin_amdgcn_mfma_f32_16x16x32_bf16(af[mt], bfr[nt],
                                                              acc[mt][nt], 0, 0, 0);
  }
#pragma unroll
  for (int nt = 0; nt < 2; ++nt) {
    int n = bn + wn * 32 + nt * 16 + l15;
    float bv = bias[n];
#pragma unroll
    for (int mt = 0; mt < 2; ++mt)
#pragma unroll
      for (int r = 0; r < 4; ++r) {
        int m = bm + wm * 32 + mt * 16 + quad * 4 + r;
        C[(size_t)m * 256 + n] = acc[mt][nt][r] + bv;
      }
  }
}

// ---------------- conv GEMM: A window staged once per k0, 3 taps from LDS ----------------
__global__ __launch_bounds__(256) void gemm_conv(const unsigned short* __restrict__ A,
                                                 const unsigned short* __restrict__ W,
                                                 const float* __restrict__ bias,
                                                 float* __restrict__ C,
                                                 float* __restrict__ stp,
                                                 float* __restrict__ stp2) {
  __shared__ __attribute__((aligned(16))) unsigned short As[80][32];   // rows circ(bm-1 ..)
  __shared__ __attribute__((aligned(16))) unsigned short Bs[192][32];  // 3 taps x 64
  int bm = blockIdx.x * 64, bn = blockIdx.y * 64;
  int tid = threadIdx.x;
  int wv = tid >> 6, lane = tid & 63;
  int wm = wv >> 1, wn = wv & 1;
  int l15 = lane & 15, quad = lane >> 4;
  int lrow = lane >> 2, lseg = lane & 3;
  int bbase = bm & ~2047, l0 = bm & 2047;
  f32x4 acc[2][2];
#pragma unroll
  for (int i = 0; i < 2; ++i)
#pragma unroll
    for (int j = 0; j < 2; ++j) acc[i][j] = (f32x4){0.f, 0.f, 0.f, 0.f};
  for (int k0 = 0; k0 < 256; k0 += 32) {
    __syncthreads();
    // A window: LDS slot i holds A[circ(bm-1+i)], i in [0,80)
    for (int c = wv; c < 5; c += 4) {
      int i0 = c * 16;
      int l = (l0 - 1 + i0 + lrow + 2048) & 2047;
      GLDS16(A + (size_t)(bbase | l) * 256 + k0 + lseg * 8, &As[i0][0]);
    }
    // B: 3 taps x 64 rows
    for (int c = wv; c < 12; c += 4) {
      int i0 = c * 16;
      int tap = c >> 2, brow = (c & 3) * 16;
      GLDS16(W + (size_t)tap * 65536 + (size_t)(bn + brow + lrow) * 256 + k0 + lseg * 8,
             &Bs[i0][0]);
    }
    __syncthreads();
#pragma unroll
    for (int tap = 0; tap < 3; ++tap) {
      short8 af[2], bfr[2];
#pragma unroll
      for (int mt = 0; mt < 2; ++mt)
        af[mt] = *(const short8*)(&As[wm * 32 + mt * 16 + l15 + tap][quad * 8]);
#pragma unroll
      for (int nt = 0; nt < 2; ++nt)
        bfr[nt] = *(const short8*)(&Bs[tap * 64 + wn * 32 + nt * 16 + l15][quad * 8]);
#pragma unroll
      for (int mt = 0; mt < 2; ++mt)
#pragma unroll
        for (int nt = 0; nt < 2; ++nt)
          acc[mt][nt] = __builtin_amdgcn_mfma_f32_16x16x32_bf16(af[mt], bfr[nt],
                                                                acc[mt][nt], 0, 0, 0);
    }
  }
#pragma unroll
  for (int nt = 0; nt < 2; ++nt) {
    int n = bn + wn * 32 + nt * 16 + l15;
    float bv = bias[n];
    float s = 0.f, s2 = 0.f;
#pragma unroll
    for (int mt = 0; mt < 2; ++mt)
#pragma unroll
      for (int r = 0; r < 4; ++r) {
        int m = bm + wm * 32 + mt * 16 + quad * 4 + r;
        float val = acc[mt][nt][r] + bv;
        C[(size_t)m * 256 + n] = val;
        s += val;
        s2 += val * val;
      }
    s  += __shfl_xor(s, 16);   s  += __shfl_xor(s, 32);
    s2 += __shfl_xor(s2, 16);  s2 += __shfl_xor(s2, 32);
    if (quad == 0) {
      atomicAdd(&stp[n], s);
      atomicAdd(&stp2[n], s2);
    }
  }
}

// ---------------- M scores: wave per (b,l), inline threefry ----------------
__global__ __launch_bounds__(256) void m_kernel3(const float* __restrict__ Q,
                                                 const float* __restrict__ K,
                                                 uint32_t k20, uint32_t k21,
                                                 float* __restrict__ M) {
  int blk = blockIdx.x;
  int b = blk >> 9, lc = blk & 511;
  int wave = threadIdx.x >> 6, lane = threadIdx.x & 63;
  int l = lc * 4 + wave;
  int myidx = 0;
  if (lane < UU) {
    int j = l * UU + lane;
    uint32_t o0, o1;
    const int half = (LL * UU) / 2;  // 40960
    if (j < half) {
      threefry2x32(k20, k21, (uint32_t)j, (uint32_t)(j + half), &o0, &o1);
      myidx = (int)(o0 & (LL - 1));
    } else {
      threefry2x32(k20, k21, (uint32_t)(j - half), (uint32_t)j, &o0, &o1);
      myidx = (int)(o1 & (LL - 1));
    }
  }
  float4 q4 = *(const float4*)(Q + ((size_t)(b * LL + l)) * DMM + lane * 4);
  const float* Kb = K + (size_t)b * LL * DMM;
  float mx = -1e30f, sm = 0.f;
#pragma unroll 4
  for (int u = 0; u < UU; ++u) {
    int kidx = __shfl(myidx, u);
    float4 k4 = *(const float4*)(Kb + (size_t)kidx * DMM + lane * 4);
    float s = q4.x * k4.x + q4.y * k4.y + q4.z * k4.z + q4.w * k4.w;
    s += __shfl_xor(s, 1);
    s += __shfl_xor(s, 2);
    s += __shfl_xor(s, 4);
    mx = fmaxf(mx, s);
    sm += s;
  }
  if ((lane & 7) == 0) {
    int h = lane >> 3;
    M[((size_t)(b * HH + h)) * LL + l] = mx - sm * (1.0f / (float)LL);
  }
}

// ---------------- fused top-k: chunk bitonic + last-block 320-merge ----------------
__global__ __launch_bounds__(256) void cand_topk(const float* __restrict__ M,
                                                 u64* __restrict__ cand,
                                                 int* __restrict__ cnt,
                                                 int* __restrict__ top,
                                                 unsigned char* __restrict__ mapb) {
  __shared__ u64 a[512];
  __shared__ int lastFlag;
  int bh = blockIdx.x >> 3, c = blockIdx.x & 7;
  int tid = threadIdx.x;
  int l = c * 256 + tid;
  {
    float v = M[(size_t)bh * LL + l];
    uint32_t bits = __float_as_uint(v);
    uint32_t kv = (bits & 0x80000000u) ? ~bits : (bits | 0x80000000u);
    a[tid] = ((u64)kv << 32) | (uint32_t)(2047 - l);
  }
  __syncthreads();
  for (int k = 2; k <= 256; k <<= 1)
    for (int j = k >> 1; j > 0; j >>= 1) {
      int ixj = tid ^ j;
      if (ixj > tid) {
        bool up = ((tid & k) == 0);
        u64 x = a[tid], y = a[ixj];
        if ((x > y) == up) { a[tid] = y; a[ixj] = x; }
      }
      __syncthreads();
    }
  if (tid >= 216) cand[(size_t)blockIdx.x * 40 + (tid - 216)] = a[tid];
  __threadfence();  // release candidate writes (device scope)
  __syncthreads();
  if (tid == 0) lastFlag = (atomicAdd(&cnt[bh], 1) == 7);
  __syncthreads();
  if (!lastFlag) return;
  __threadfence();  // acquire other blocks' candidates
  for (int t = tid; t < 2048; t += 256) mapb[bh * 2048 + t] = 0;
  for (int t = tid; t < 512; t += 256)
    a[t] = (t < 320) ? cand[(size_t)(bh * 8) * 40 + t] : 0ULL;
  __syncthreads();
  for (int k = 2; k <= 512; k <<= 1)
    for (int j = k >> 1; j > 0; j >>= 1) {
      for (int t = tid; t < 512; t += 256) {
        int ixj = t ^ j;
        if (ixj > t) {
          bool up = ((t & k) == 0);
          u64 x = a[t], y = a[ixj];
          if ((x > y) == up) { a[t] = y; a[ixj] = x; }
        }
      }
      __syncthreads();
    }
  if (tid < UU) {
    u64 key = a[511 - tid];
    int ll = 2047 - (int)(uint32_t)(key & 0xFFFFFFFFu);
    top[bh * UU + tid] = ll;
    mapb[bh * 2048 + ll] = (unsigned char)(tid + 1);
  }
}

// ---------------- split-K flash attention: partials (bf16 V) ----------------
__global__ __launch_bounds__(256) void attn_part(const float* __restrict__ Q,
                                                 const float* __restrict__ K,
                                                 const unsigned short* __restrict__ Vbf,
                                                 const int* __restrict__ top,
                                                 float* __restrict__ pm,
                                                 float* __restrict__ pl,
                                                 float* __restrict__ po) {
  __shared__ float Qs[40][32];
  __shared__ unsigned short ps[40][256];
  __shared__ unsigned short Vs[256][40];
  __shared__ int qrows[40];
  int kc = blockIdx.x, bh = blockIdx.y;
  int h = bh & 7, b = bh >> 3;
  int tid = threadIdx.x;
  int wv = tid >> 6, lane = tid & 63;
  if (tid < 40) qrows[tid] = top[bh * UU + tid];
  __syncthreads();
  for (int t = tid; t < 40 * 32; t += 256) {
    int q = t >> 5, d = t & 31;
    Qs[q][d] = Q[((size_t)(b * LL + qrows[q])) * DMM + h * EE + d];
  }
  {
    int krow = b * LL + kc * 256 + tid;
    const uint4* vp = (const uint4*)(Vbf + (size_t)krow * DMM + h * EE);
#pragma unroll
    for (int seg = 0; seg < 4; ++seg)
      *(uint4*)(&Vs[tid][seg * 8]) = vp[seg];
  }
  __syncthreads();
  {
    const float4* kp =
        (const float4*)(K + ((size_t)(b * LL + kc * 256 + tid)) * DMM + h * EE);
    float4 kr[8];
#pragma unroll
    for (int j = 0; j < 8; ++j) kr[j] = kp[j];
    const float scale = 0.17677669529663687f;
    for (int q = 0; q < 40; ++q) {
      const float4* qp = (const float4*)Qs[q];
      float s = 0.f;
#pragma unroll
      for (int j = 0; j < 8; ++j) {
        float4 qv = qp[j];
        s += qv.x * kr[j].x + qv.y * kr[j].y + qv.z * kr[j].z + qv.w * kr[j].w;
      }
      ps[q][tid] = f2b(s * scale);
    }
  }
  __syncthreads();
  int kg = lane >> 5, d = lane & 31;
  for (int qq = 0; qq < 10; ++qq) {
    int q = wv * 10 + qq;
    float mx = -1e30f;
#pragma unroll
    for (int e = 0; e < 4; ++e) mx = fmaxf(mx, bfbits(ps[q][lane + 64 * e]));
#pragma unroll
    for (int off = 32; off > 0; off >>= 1) mx = fmaxf(mx, __shfl_xor(mx, off));
    float sum = 0.f;
#pragma unroll
    for (int e = 0; e < 4; ++e) {
      int i = lane + 64 * e;
      float ev = expf(bfbits(ps[q][i]) - mx);
      sum += ev;
      ps[q][i] = f2b(ev);
    }
    sum = wave_sum(sum);
    float o = 0.f;
#pragma unroll 8
    for (int j = 0; j < 128; ++j) {
      int r = 2 * j + kg;
      o += bfbits(ps[q][r]) * bfbits(Vs[r][d]);
    }
    o += __shfl_xor(o, 32);
    size_t base = ((size_t)bh * UU + q) * 8 + kc;
    if (lane == 0) { pm[base] = mx; pl[base] = sum; }
    if (lane < 32) po[base * 32 + d] = o;
  }
}

// ---------------- fused LN1(x+t) + FFN + LN2 (+final LN, +stat zero) ----------------
__global__ __launch_bounds__(256) void enc_tail(const float* __restrict__ X,
                                                const float* __restrict__ T,
                                                const float* __restrict__ g1,
                                                const float* __restrict__ b1ln,
                                                const float* __restrict__ w1,
                                                const float* __restrict__ b1,
                                                const float* __restrict__ w2,
                                                const float* __restrict__ b2,
                                                const float* __restrict__ g2,
                                                const float* __restrict__ b2ln,
                                                float* __restrict__ Out,
                                                unsigned short* __restrict__ OutB,
                                                unsigned short* __restrict__ OutL,
                                                const float* __restrict__ fing,
                                                const float* __restrict__ finb,
                                                void* __restrict__ finOut,
                                                const int* __restrict__ flag,
                                                float* __restrict__ stpZ,
                                                float* __restrict__ stp2Z) {
  if (blockIdx.x == 0) {
    stpZ[threadIdx.x] = 0.f;
    stp2Z[threadIdx.x] = 0.f;
  }
  int wave = threadIdx.x >> 6, lane = threadIdx.x & 63;
  size_t row = (size_t)blockIdx.x * 4 + wave;
  __shared__ float xs[4][DMM];
  const float* xr = X + row * DMM;
  const float* tr = T + row * DMM;
  float v[4];
#pragma unroll
  for (int i = 0; i < 4; ++i) v[i] = xr[lane + 64 * i] + tr[lane + 64 * i];
  float s = wave_sum(v[0] + v[1] + v[2] + v[3]);
  float m = s * (1.0f / (float)DMM);
  float sq = 0.f;
#pragma unroll
  for (int i = 0; i < 4; ++i) { float d = v[i] - m; sq += d * d; }
  sq = wave_sum(sq);
  float rstd = rsqrtf(sq * (1.0f / (float)DMM) + 1e-5f);
  float xv[4];
#pragma unroll
  for (int i = 0; i < 4; ++i) {
    int d = lane + 64 * i;
    xv[i] = (v[i] - m) * rstd * g1[d] + b1ln[d];
    xs[wave][d] = xv[i];
  }
  __syncthreads();
  int f = lane & 15, qtr = lane >> 4;
  const float* w1p = w1 + f * DMM + qtr * 64;
  const float* xq = &xs[wave][qtr * 64];
  float pacc = 0.f;
#pragma unroll 8
  for (int d = 0; d < 64; ++d) pacc += xq[d] * w1p[d];
  pacc += __shfl_xor(pacc, 16);
  pacc += __shfl_xor(pacc, 32);
  float y1 = fmaxf(pacc + b1[f], 0.0f);
  float y1v[16];
#pragma unroll
  for (int ff = 0; ff < 16; ++ff) y1v[ff] = __shfl(y1, ff);
#pragma unroll
  for (int i = 0; i < 4; ++i) {
    int d = lane + 64 * i;
    const float* w2p = w2 + d * ITR;
    float a = b2[d];
#pragma unroll
    for (int ff = 0; ff < 16; ++ff) a += y1v[ff] * w2p[ff];
    v[i] = xv[i] + a;
  }
  s = wave_sum(v[0] + v[1] + v[2] + v[3]);
  m = s * (1.0f / (float)DMM);
  sq = 0.f;
#pragma unroll
  for (int i = 0; i < 4; ++i) { float d = v[i] - m; sq += d * d; }
  sq = wave_sum(sq);
  rstd = rsqrtf(sq * (1.0f / (float)DMM) + 1e-5f);
  float vv[4];
#pragma unroll
  for (int i = 0; i < 4; ++i) {
    int d = lane + 64 * i;
    float val = (v[i] - m) * rstd * g2[d] + b2ln[d];
    vv[i] = val;
    Out[row * DMM + d] = val;
    unsigned short hi = f2b(val);
    OutB[row * DMM + d] = hi;
    OutL[row * DMM + d] = f2b(val - bfbits(hi));
  }
  if (finOut) {
    s = wave_sum(vv[0] + vv[1] + vv[2] + vv[3]);
    m = s * (1.0f / (float)DMM);
    sq = 0.f;
#pragma unroll
    for (int i = 0; i < 4; ++i) { float d = vv[i] - m; sq += d * d; }
    sq = wave_sum(sq);
    rstd = rsqrtf(sq * (1.0f / (float)DMM) + 1e-5f);
    int isf32 = *flag;
#pragma unroll
    for (int i = 0; i < 4; ++i) {
      int d = lane + 64 * i;
      float val = (vv[i] - m) * rstd * fing[d] + finb[d];
      if (isf32) ((float*)finOut)[row * DMM + d] = val;
      else       ((unsigned short*)finOut)[row * DMM + d] = f2b(val);
    }
  }
}

// ---------------- bn+elu from atomic stats (+vmp zero for next layer) ----------------
__global__ __launch_bounds__(256) void bn_elu(const float* __restrict__ Y,
                                              const float* __restrict__ stp,
                                              const float* __restrict__ stp2,
                                              const float* __restrict__ g,
                                              const float* __restrict__ bb,
                                              float* __restrict__ X,
                                              unsigned short* __restrict__ XB,
                                              unsigned short* __restrict__ XL,
                                              float* __restrict__ vmpZ) {
  int gid = blockIdx.x * 256 + threadIdx.x;
  if (gid < BB * DMM) vmpZ[gid] = 0.f;
  int d = gid & 255;
  float mean = stp[d] * (1.0f / (float)ROWS);
  float var = stp2[d] * (1.0f / (float)ROWS) - mean * mean;
  float rstd = rsqrtf(var + 1e-5f);
  float v = (Y[gid] - mean) * rstd * g[d] + bb[d];
  float r = v > 0.f ? v : expm1f(v);
  X[gid] = r;
  unsigned short hi = f2b(r);
  XB[gid] = hi;
  XL[gid] = f2b(r - bfbits(hi));
}

extern "C" void kernel_launch(void* const* d_in, const int* in_sizes, int n_in,
                              void* d_out, int out_size, void* d_ws, size_t ws_size,
                              hipStream_t stream) {
  (void)in_sizes; (void)n_in; (void)out_size; (void)ws_size;

  // ---- workspace layout ----
  float* xbuf = (float*)d_ws;
  float* kb   = xbuf + NELEM;
  float* qb   = kb + NELEM;   // aliases tmp (Q dead after attn_part)
  float* tmp  = qb;
  float* Mbuf = qb + NELEM;
  float* vmp  = Mbuf + BB * HH * LL;
  float* stp  = vmp + BB * DMM;
  float* stp2 = stp + DMM;
  float* wp   = stp2 + DMM;
  const int wsz[23] = {
      NELEM,
      NLL * DMM * DMM, NLL * DMM,
      NLL * DMM * DMM, NLL * DMM,
      NLL * DMM * DMM, NLL * DMM,
      NLL * DMM * DMM, NLL * DMM,
      NLL * ITR * DMM, NLL * ITR,
      NLL * DMM * ITR, NLL * DMM,
      NLL * DMM, NLL * DMM,
      NLL * DMM, NLL * DMM,
      (NLL - 1) * DMM * DMM * 3, (NLL - 1) * DMM,
      (NLL - 1) * DMM, (NLL - 1) * DMM,
      DMM, DMM
  };
  float* fptr[23];
  fptr[0] = xbuf;
  for (int i = 1; i < 23; ++i) { fptr[i] = wp; wp += wsz[i]; }
  float* pm = wp;
  float* pl = pm + 32 * UU * 8;
  float* po = pl + 32 * UU * 8;
  unsigned short* xbf   = (unsigned short*)(po + 32 * UU * 8 * 32);
  unsigned short* xlo   = xbf + NELEM;
  unsigned short* vbf   = xlo + NELEM;
  unsigned short* wqbf  = vbf + NELEM;
  unsigned short* wkbf  = wqbf + NLL * DMM * DMM;
  unsigned short* wvbf  = wkbf + NLL * DMM * DMM;
  unsigned short* wobf  = wvbf + NLL * DMM * DMM;
  unsigned short* dcwT  = wobf + NLL * DMM * DMM;
  u64* cand = (u64*)(dcwT + (NLL - 1) * 3 * DMM * DMM);  // 256*40
  int* topb = (int*)(cand + 256 * 40);
  int* cnts = topb + BB * HH * UU;   // NLL*32
  int* flag = cnts + NLL * 32;
  unsigned char* mapb = (unsigned char*)(flag + 1);  // 32*2048

  // ---- probe + convert (+dcw repack, +vmp/cnt zero) ----
  probe_dtype<<<1, 256, 0, stream>>>(d_in[0], flag);
  CvtArgs ca;
  int totalBlk = 0;
  for (int i = 0; i < 23; ++i) {
    ca.src[i] = d_in[i];
    ca.dstF[i] = fptr[i];
    ca.dstB[i] = nullptr;
    ca.dstL[i] = nullptr;
    ca.n[i] = wsz[i];
    ca.blkStart[i] = totalBlk;
    totalBlk += (wsz[i] + 255) / 256;
  }
  ca.blkStart[23] = totalBlk;
  ca.dstB[0] = xbf;  ca.dstL[0] = xlo;
  ca.dstB[1] = wqbf;
  ca.dstB[3] = wkbf;
  ca.dstB[5] = wvbf;
  ca.dstB[7] = wobf;
  ca.dcwT = dcwT;
  ca.vmpZ = vmp;
  ca.cntZ = cnts;
  mega_cvt<<<totalBlk + 1, 256, 0, stream>>>(ca, flag);

  dim3 gqkv(ROWS / 128, DMM / 64, 3);
  dim3 g64(ROWS / 64, DMM / 64);

  for (int i = 0; i < NLL; ++i) {
    QKVArgs qa;
    qa.W[0] = wqbf + (size_t)i * DMM * DMM;
    qa.W[1] = wkbf + (size_t)i * DMM * DMM;
    qa.W[2] = wvbf + (size_t)i * DMM * DMM;
    qa.bias[0] = fptr[2] + i * DMM;
    qa.bias[1] = fptr[4] + i * DMM;
    qa.bias[2] = fptr[6] + i * DMM;
    qa.Cq = qb; qa.Ck = kb; qa.Cv = vbf;
    qa.vmp = vmp;
    gemm_qkv<<<gqkv, 256, 0, stream>>>(xbf, xlo, qa);

    uint32_t ki0, ki1, a0, a1, b0, b1;
    threefry2x32(0u, 42u, 0u, (uint32_t)i, &ki0, &ki1);
    threefry2x32(ki0, ki1, 0u, 2u, &a0, &a1);
    threefry2x32(ki0, ki1, 1u, 3u, &b0, &b1);
    (void)a0; (void)b0;

    m_kernel3<<<BB * 512, 256, 0, stream>>>(qb, kb, a1, b1, Mbuf);
    cand_topk<<<BB * HH * 8, 256, 0, stream>>>(Mbuf, cand, cnts + i * 32, topb, mapb);
    attn_part<<<dim3(8, BB * HH), 256, 0, stream>>>(qb, kb, vbf, topb, pm, pl, po);

    gemm_oproj<<<g64, 256, 0, stream>>>(vmp, mapb, pm, pl, po,
                                        wobf + (size_t)i * DMM * DMM,
                                        fptr[8] + i * DMM, tmp);
    bool last = (i == NLL - 1);
    enc_tail<<<ROWS / 4, 256, 0, stream>>>(
        xbuf, tmp, fptr[13] + i * DMM, fptr[14] + i * DMM,
        fptr[9] + (size_t)i * ITR * DMM, fptr[10] + i * ITR,
        fptr[11] + (size_t)i * DMM * ITR, fptr[12] + i * DMM,
        fptr[15] + i * DMM, fptr[16] + i * DMM, xbuf, xbf, xlo,
        fptr[21], fptr[22], last ? d_out : nullptr, flag, stp, stp2);

    if (!last) {
      gemm_conv<<<g64, 256, 0, stream>>>(xbf, dcwT + (size_t)i * 3 * DMM * DMM,
                                         fptr[18] + i * DMM, tmp, stp, stp2);
      bn_elu<<<NELEM / 256, 256, 0, stream>>>(tmp, stp, stp2, fptr[19] + i * DMM,
                                              fptr[20] + i * DMM, xbuf, xbf, xlo, vmp);
    }
  }
}

// Round 12
// 579.543 us; speedup vs baseline: 1.0825x; 1.0825x over previous
//
#include <hip/hip_runtime.h>
#include <stdint.h>

#define BB 4
#define LL 2048
#define DMM 256
#define HH 8
#define EE 32
#define NLL 3
#define ITR 16
#define UU 40
#define ROWS (BB*LL)          // 8192
#define NELEM (ROWS*DMM)      // 2097152

typedef __attribute__((ext_vector_type(8))) short short8;
typedef __attribute__((ext_vector_type(4))) float f32x4;
typedef unsigned long long u64;

#define GLDS16(g, l)                                                        \
  __builtin_amdgcn_global_load_lds(                                         \
      (const __attribute__((address_space(1))) uint32_t*)(g),               \
      (__attribute__((address_space(3))) uint32_t*)(l), 16, 0, 0)

// ---------------- bf16 bit helpers (RNE) ----------------
__device__ __forceinline__ float bfbits(unsigned short u) {
  return __uint_as_float(((uint32_t)u) << 16);
}
__device__ __forceinline__ unsigned short f2b(float f) {
  uint32_t u = __float_as_uint(f);
  uint32_t r = (u + 0x7FFFu + ((u >> 16) & 1u)) >> 16;
  return (unsigned short)r;
}

// ---------------- threefry2x32 (exact JAX semantics) ----------------
__host__ __device__ inline void threefry2x32(uint32_t k0, uint32_t k1,
                                             uint32_t x0, uint32_t x1,
                                             uint32_t* o0, uint32_t* o1) {
  uint32_t ks2 = k0 ^ k1 ^ 0x1BD11BDAu;
  x0 += k0; x1 += k1;
#define TFR(r) { x0 += x1; x1 = (x1 << (r)) | (x1 >> (32 - (r))); x1 ^= x0; }
  TFR(13) TFR(15) TFR(26) TFR(6)
  x0 += k1;  x1 += ks2 + 1u;
  TFR(17) TFR(29) TFR(16) TFR(24)
  x0 += ks2; x1 += k0 + 2u;
  TFR(13) TFR(15) TFR(26) TFR(6)
  x0 += k0;  x1 += k1 + 3u;
  TFR(17) TFR(29) TFR(16) TFR(24)
  x0 += k1;  x1 += ks2 + 4u;
  TFR(13) TFR(15) TFR(26) TFR(6)
  x0 += ks2; x1 += k0 + 5u;
#undef TFR
  *o0 = x0; *o1 = x1;
}

__device__ __forceinline__ float wave_sum(float v) {
#pragma unroll
  for (int off = 32; off > 0; off >>= 1) v += __shfl_xor(v, off);
  return v;
}

// ---------------- dtype probe ----------------
__global__ __launch_bounds__(256) void probe_dtype(const void* __restrict__ x,
                                                   int* __restrict__ flag) {
  __shared__ int cnt;
  if (threadIdx.x == 0) cnt = 0;
  __syncthreads();
  const unsigned short* u = (const unsigned short*)x;
  int bad = 0;
  for (int j = threadIdx.x; j < 2048; j += 256) {
    float v = bfbits(u[j]);
    float a = fabsf(v);
    bool ok = (v == 0.0f) || (a > 1e-4f && a < 100.0f);
    if (!ok) bad++;
  }
  atomicAdd(&cnt, bad);
  __syncthreads();
  if (threadIdx.x == 0) *flag = (cnt > 100) ? 1 : 0;
}

// ---------------- mega convert (+hi/lo splits, +dcw repack, +vmp zero) ----------------
struct CvtArgs {
  const void* src[23];
  float* dstF[23];
  unsigned short* dstB[23];
  unsigned short* dstL[23];
  int n[23];
  int blkStart[24];
  unsigned short* dcwT;
  float* vmpZ;     // zero BB*DMM floats
};
__global__ __launch_bounds__(256) void mega_cvt(CvtArgs a, const int* __restrict__ flag) {
  int bid = blockIdx.x;
  if (bid == a.blkStart[23]) {
    for (int t = threadIdx.x; t < BB * DMM; t += 256) a.vmpZ[t] = 0.f;
    return;
  }
  int i = 0;
  while (i < 22 && bid >= a.blkStart[i + 1]) ++i;
  int e = (bid - a.blkStart[i]) * 256 + (int)threadIdx.x;
  if (e >= a.n[i]) return;
  float v; unsigned short rw;
  if (*flag) { v = ((const float*)a.src[i])[e]; rw = f2b(v); }
  else       { rw = ((const unsigned short*)a.src[i])[e]; v = bfbits(rw); }
  a.dstF[i][e] = v;
  if (a.dstB[i]) a.dstB[i][e] = rw;
  if (a.dstL[i]) a.dstL[i][e] = f2b(v - bfbits(rw));
  if (i == 17) {  // dcw: [ly][n][k][t] -> [ly][t][n][k] bf16
    int ly = e / 196608;
    int r = e - ly * 196608;
    int n = r / 768;
    int rem = r - n * 768;
    int k = rem / 3, t = rem - k * 3;
    a.dcwT[ly * 196608 + t * 65536 + n * 256 + k] = rw;
  }
}

// ---------------- QKV MFMA GEMM: z=0:Q 1:K (hi/lo 2-pass, f32 out) 2:V (bf16 out + vmean) --
struct QKVArgs {
  const unsigned short* W[3];
  const float* bias[3];
  float* Cq;
  float* Ck;
  unsigned short* Cv;
  float* vmp;
};
__global__ __launch_bounds__(256) void gemm_qkv(const unsigned short* __restrict__ Ahi,
                                                const unsigned short* __restrict__ Alo,
                                                QKVArgs qa) {
  __shared__ __attribute__((aligned(16))) unsigned short AsH[128][32];
  __shared__ __attribute__((aligned(16))) unsigned short AsL[128][32];
  __shared__ __attribute__((aligned(16))) unsigned short Bs[64][32];
  int z = blockIdx.z;
  const unsigned short* W = qa.W[z];
  const float* bias = qa.bias[z];
  bool twoPass = (z < 2);
  int bm = blockIdx.x * 128, bn = blockIdx.y * 64;
  int tid = threadIdx.x;
  int wv = tid >> 6, lane = tid & 63;
  int wm = wv >> 1, wn = wv & 1;
  int l15 = lane & 15, quad = lane >> 4;
  int lrow = lane >> 2, lseg = lane & 3;
  f32x4 acc[4][2];
#pragma unroll
  for (int i = 0; i < 4; ++i)
#pragma unroll
    for (int j = 0; j < 2; ++j) acc[i][j] = (f32x4){0.f, 0.f, 0.f, 0.f};
  for (int k0 = 0; k0 < 256; k0 += 32) {
    __syncthreads();
#pragma unroll
    for (int s = 0; s < 2; ++s) {
      int brow = (wv + s * 4) * 16;
      size_t goff = (size_t)(bm + brow + lrow) * 256 + k0 + lseg * 8;
      GLDS16(Ahi + goff, &AsH[brow][0]);
      if (twoPass) GLDS16(Alo + goff, &AsL[brow][0]);
    }
    {
      int brow = wv * 16;
      GLDS16(W + (size_t)(bn + brow + lrow) * 256 + k0 + lseg * 8, &Bs[brow][0]);
    }
    __syncthreads();
    short8 ah[4], bfr[2];
#pragma unroll
    for (int mt = 0; mt < 4; ++mt)
      ah[mt] = *(const short8*)(&AsH[wm * 64 + mt * 16 + l15][quad * 8]);
#pragma unroll
    for (int nt = 0; nt < 2; ++nt)
      bfr[nt] = *(const short8*)(&Bs[wn * 32 + nt * 16 + l15][quad * 8]);
#pragma unroll
    for (int mt = 0; mt < 4; ++mt)
#pragma unroll
      for (int nt = 0; nt < 2; ++nt)
        acc[mt][nt] = __builtin_amdgcn_mfma_f32_16x16x32_bf16(ah[mt], bfr[nt],
                                                              acc[mt][nt], 0, 0, 0);
    if (twoPass) {
      short8 al[4];
#pragma unroll
      for (int mt = 0; mt < 4; ++mt)
        al[mt] = *(const short8*)(&AsL[wm * 64 + mt * 16 + l15][quad * 8]);
#pragma unroll
      for (int mt = 0; mt < 4; ++mt)
#pragma unroll
        for (int nt = 0; nt < 2; ++nt)
          acc[mt][nt] = __builtin_amdgcn_mfma_f32_16x16x32_bf16(al[mt], bfr[nt],
                                                                acc[mt][nt], 0, 0, 0);
    }
  }
  float* C = (z == 0) ? qa.Cq : qa.Ck;
#pragma unroll
  for (int nt = 0; nt < 2; ++nt) {
    int n = bn + wn * 32 + nt * 16 + l15;
    float bv = bias[n];
    float csum = 0.f;
#pragma unroll
    for (int mt = 0; mt < 4; ++mt)
#pragma unroll
      for (int r = 0; r < 4; ++r) {
        int m = bm + wm * 64 + mt * 16 + quad * 4 + r;
        float val = acc[mt][nt][r] + bv;
        if (z < 2) {
          C[(size_t)m * 256 + n] = val;
        } else {
          qa.Cv[(size_t)m * 256 + n] = f2b(val);
          csum += val;
        }
      }
    if (z == 2) {
      csum += __shfl_xor(csum, 16);
      csum += __shfl_xor(csum, 32);
      if (quad == 0) {
        int b = bm >> 11;
        atomicAdd(&qa.vmp[b * DMM + n], csum);
      }
    }
  }
}

// ---------------- O-proj GEMM with on-the-fly ctx A-tiles ----------------
__global__ __launch_bounds__(256) void gemm_oproj(const float* __restrict__ vmp,
                                                  const unsigned char* __restrict__ mapb,
                                                  const float* __restrict__ pm,
                                                  const float* __restrict__ pl,
                                                  const float* __restrict__ po,
                                                  const unsigned short* __restrict__ W,
                                                  const float* __restrict__ bias,
                                                  float* __restrict__ C) {
  __shared__ __attribute__((aligned(16))) unsigned short As[64][32];
  __shared__ __attribute__((aligned(16))) unsigned short Bs[64][32];
  int bm = blockIdx.x * 64, bn = blockIdx.y * 64;
  int tid = threadIdx.x;
  int wv = tid >> 6, lane = tid & 63;
  int wm = wv >> 1, wn = wv & 1;
  int l15 = lane & 15, quad = lane >> 4;
  int lrow = lane >> 2, lseg = lane & 3;
  int arow = tid >> 2, adg = tid & 3;
  int b = bm >> 11, l0 = bm & 2047;
  const float invL = 1.0f / (float)LL;
  f32x4 acc[2][2];
#pragma unroll
  for (int i = 0; i < 2; ++i)
#pragma unroll
    for (int j = 0; j < 2; ++j) acc[i][j] = (f32x4){0.f, 0.f, 0.f, 0.f};
  for (int k0 = 0; k0 < 256; k0 += 32) {
    int h = k0 >> 5;
    int bh = b * HH + h;
    __syncthreads();
    {
      int l = l0 + arow;
      int q = (int)mapb[bh * 2048 + l];
      unsigned short outv[8];
      if (q) {
        size_t base = ((size_t)bh * UU + (q - 1)) * 8;
        float Mx = -1e30f;
#pragma unroll
        for (int kc = 0; kc < 8; ++kc) Mx = fmaxf(Mx, pm[base + kc]);
        float Ls = 0.f;
        float sc[8];
#pragma unroll
        for (int kc = 0; kc < 8; ++kc) {
          sc[kc] = expf(pm[base + kc] - Mx);
          Ls += pl[base + kc] * sc[kc];
        }
        float inv = 1.0f / Ls;
#pragma unroll
        for (int j = 0; j < 8; ++j) {
          int dl = adg * 8 + j;
          float o = 0.f;
#pragma unroll
          for (int kc = 0; kc < 8; ++kc) o += po[(base + kc) * 32 + dl] * sc[kc];
          outv[j] = f2b(o * inv);
        }
      } else {
        const float* vp = vmp + b * DMM + h * EE + adg * 8;
#pragma unroll
        for (int j = 0; j < 8; ++j) outv[j] = f2b(vp[j] * invL);
      }
      *(uint4*)(&As[arow][adg * 8]) = *(const uint4*)outv;
    }
    {
      int brow = wv * 16;
      GLDS16(W + (size_t)(bn + brow + lrow) * 256 + k0 + lseg * 8, &Bs[brow][0]);
    }
    __syncthreads();
    short8 af[2], bfr[2];
#pragma unroll
    for (int mt = 0; mt < 2; ++mt)
      af[mt] = *(const short8*)(&As[wm * 32 + mt * 16 + l15][quad * 8]);
#pragma unroll
    for (int nt = 0; nt < 2; ++nt)
      bfr[nt] = *(const short8*)(&Bs[wn * 32 + nt * 16 + l15][quad * 8]);
#pragma unroll
    for (int mt = 0; mt < 2; ++mt)
#pragma unroll
      for (int nt = 0; nt < 2; ++nt)
        acc[mt][nt] = __builtin_amdgcn_mfma_f32_16x16x32_bf16(af[mt], bfr[nt],
                                                              acc[mt][nt], 0, 0, 0);
  }
#pragma unroll
  for (int nt = 0; nt < 2; ++nt) {
    int n = bn + wn * 32 + nt * 16 + l15;
    float bv = bias[n];
#pragma unroll
    for (int mt = 0; mt < 2; ++mt)
#pragma unroll
      for (int r = 0; r < 4; ++r) {
        int m = bm + wm * 32 + mt * 16 + quad * 4 + r;
        C[(size_t)m * 256 + n] = acc[mt][nt][r] + bv;
      }
  }
}

// ---------------- conv GEMM: A window staged once per k0, 3 taps from LDS ----------------
__global__ __launch_bounds__(256) void gemm_conv(const unsigned short* __restrict__ A,
                                                 const unsigned short* __restrict__ W,
                                                 const float* __restrict__ bias,
                                                 float* __restrict__ C,
                                                 float* __restrict__ stp,
                                                 float* __restrict__ stp2) {
  __shared__ __attribute__((aligned(16))) unsigned short As[80][32];
  __shared__ __attribute__((aligned(16))) unsigned short Bs[192][32];
  int bm = blockIdx.x * 64, bn = blockIdx.y * 64;
  int tid = threadIdx.x;
  int wv = tid >> 6, lane = tid & 63;
  int wm = wv >> 1, wn = wv & 1;
  int l15 = lane & 15, quad = lane >> 4;
  int lrow = lane >> 2, lseg = lane & 3;
  int bbase = bm & ~2047, l0 = bm & 2047;
  f32x4 acc[2][2];
#pragma unroll
  for (int i = 0; i < 2; ++i)
#pragma unroll
    for (int j = 0; j < 2; ++j) acc[i][j] = (f32x4){0.f, 0.f, 0.f, 0.f};
  for (int k0 = 0; k0 < 256; k0 += 32) {
    __syncthreads();
    for (int c = wv; c < 5; c += 4) {
      int i0 = c * 16;
      int l = (l0 - 1 + i0 + lrow + 2048) & 2047;
      GLDS16(A + (size_t)(bbase | l) * 256 + k0 + lseg * 8, &As[i0][0]);
    }
    for (int c = wv; c < 12; c += 4) {
      int i0 = c * 16;
      int tap = c >> 2, brow = (c & 3) * 16;
      GLDS16(W + (size_t)tap * 65536 + (size_t)(bn + brow + lrow) * 256 + k0 + lseg * 8,
             &Bs[i0][0]);
    }
    __syncthreads();
#pragma unroll
    for (int tap = 0; tap < 3; ++tap) {
      short8 af[2], bfr[2];
#pragma unroll
      for (int mt = 0; mt < 2; ++mt)
        af[mt] = *(const short8*)(&As[wm * 32 + mt * 16 + l15 + tap][quad * 8]);
#pragma unroll
      for (int nt = 0; nt < 2; ++nt)
        bfr[nt] = *(const short8*)(&Bs[tap * 64 + wn * 32 + nt * 16 + l15][quad * 8]);
#pragma unroll
      for (int mt = 0; mt < 2; ++mt)
#pragma unroll
        for (int nt = 0; nt < 2; ++nt)
          acc[mt][nt] = __builtin_amdgcn_mfma_f32_16x16x32_bf16(af[mt], bfr[nt],
                                                                acc[mt][nt], 0, 0, 0);
    }
  }
#pragma unroll
  for (int nt = 0; nt < 2; ++nt) {
    int n = bn + wn * 32 + nt * 16 + l15;
    float bv = bias[n];
    float s = 0.f, s2 = 0.f;
#pragma unroll
    for (int mt = 0; mt < 2; ++mt)
#pragma unroll
      for (int r = 0; r < 4; ++r) {
        int m = bm + wm * 32 + mt * 16 + quad * 4 + r;
        float val = acc[mt][nt][r] + bv;
        C[(size_t)m * 256 + n] = val;
        s += val;
        s2 += val * val;
      }
    s  += __shfl_xor(s, 16);   s  += __shfl_xor(s, 32);
    s2 += __shfl_xor(s2, 16);  s2 += __shfl_xor(s2, 32);
    if (quad == 0) {
      atomicAdd(&stp[n], s);
      atomicAdd(&stp2[n], s2);
    }
  }
}

// ---------------- M scores: wave per (b,l), inline threefry ----------------
__global__ __launch_bounds__(256) void m_kernel3(const float* __restrict__ Q,
                                                 const float* __restrict__ K,
                                                 uint32_t k20, uint32_t k21,
                                                 float* __restrict__ M) {
  int blk = blockIdx.x;
  int b = blk >> 9, lc = blk & 511;
  int wave = threadIdx.x >> 6, lane = threadIdx.x & 63;
  int l = lc * 4 + wave;
  int myidx = 0;
  if (lane < UU) {
    int j = l * UU + lane;
    uint32_t o0, o1;
    const int half = (LL * UU) / 2;  // 40960
    if (j < half) {
      threefry2x32(k20, k21, (uint32_t)j, (uint32_t)(j + half), &o0, &o1);
      myidx = (int)(o0 & (LL - 1));
    } else {
      threefry2x32(k20, k21, (uint32_t)(j - half), (uint32_t)j, &o0, &o1);
      myidx = (int)(o1 & (LL - 1));
    }
  }
  float4 q4 = *(const float4*)(Q + ((size_t)(b * LL + l)) * DMM + lane * 4);
  const float* Kb = K + (size_t)b * LL * DMM;
  float mx = -1e30f, sm = 0.f;
#pragma unroll 4
  for (int u = 0; u < UU; ++u) {
    int kidx = __shfl(myidx, u);
    float4 k4 = *(const float4*)(Kb + (size_t)kidx * DMM + lane * 4);
    float s = q4.x * k4.x + q4.y * k4.y + q4.z * k4.z + q4.w * k4.w;
    s += __shfl_xor(s, 1);
    s += __shfl_xor(s, 2);
    s += __shfl_xor(s, 4);
    mx = fmaxf(mx, s);
    sm += s;
  }
  if ((lane & 7) == 0) {
    int h = lane >> 3;
    M[((size_t)(b * HH + h)) * LL + l] = mx - sm * (1.0f / (float)LL);
  }
}

// ---------------- top-k stage A: per-256-chunk bitonic, emit top-40 ----------------
__global__ __launch_bounds__(256) void cand_topk(const float* __restrict__ M,
                                                 u64* __restrict__ cand) {
  __shared__ u64 a[256];
  int bh = blockIdx.x >> 3, c = blockIdx.x & 7;
  int tid = threadIdx.x;
  int l = c * 256 + tid;
  float v = M[(size_t)bh * LL + l];
  uint32_t bits = __float_as_uint(v);
  uint32_t kv = (bits & 0x80000000u) ? ~bits : (bits | 0x80000000u);
  a[tid] = ((u64)kv << 32) | (uint32_t)(2047 - l);
  __syncthreads();
  for (int k = 2; k <= 256; k <<= 1)
    for (int j = k >> 1; j > 0; j >>= 1) {
      int ixj = tid ^ j;
      if (ixj > tid) {
        bool up = ((tid & k) == 0);
        u64 x = a[tid], y = a[ixj];
        if ((x > y) == up) { a[tid] = y; a[ixj] = x; }
      }
      __syncthreads();
    }
  if (tid >= 216) cand[(size_t)blockIdx.x * 40 + (tid - 216)] = a[tid];
}

// ---------------- top-k stage B: merge 320 candidates (+selection map) ----------------
__global__ __launch_bounds__(256) void merge_topk(const u64* __restrict__ cand,
                                                  int* __restrict__ top,
                                                  unsigned char* __restrict__ mapb) {
  __shared__ u64 a[512];
  int bh = blockIdx.x;
  int tid = threadIdx.x;
  for (int t = tid; t < 2048; t += 256) mapb[bh * 2048 + t] = 0;
  for (int t = tid; t < 512; t += 256)
    a[t] = (t < 320) ? cand[(size_t)bh * 320 + t] : 0ULL;
  __syncthreads();
  for (int k = 2; k <= 512; k <<= 1)
    for (int j = k >> 1; j > 0; j >>= 1) {
      for (int t = tid; t < 512; t += 256) {
        int ixj = t ^ j;
        if (ixj > t) {
          bool up = ((t & k) == 0);
          u64 x = a[t], y = a[ixj];
          if ((x > y) == up) { a[t] = y; a[ixj] = x; }
        }
      }
      __syncthreads();
    }
  if (tid < UU) {
    u64 key = a[511 - tid];
    int l = 2047 - (int)(uint32_t)(key & 0xFFFFFFFFu);
    top[bh * UU + tid] = l;
    mapb[bh * 2048 + l] = (unsigned char)(tid + 1);
  }
}

// ---------------- split-K flash attention: partials (bf16 V) ----------------
__global__ __launch_bounds__(256) void attn_part(const float* __restrict__ Q,
                                                 const float* __restrict__ K,
                                                 const unsigned short* __restrict__ Vbf,
                                                 const int* __restrict__ top,
                                                 float* __restrict__ pm,
                                                 float* __restrict__ pl,
                                                 float* __restrict__ po) {
  __shared__ float Qs[40][32];
  __shared__ unsigned short ps[40][256];
  __shared__ unsigned short Vs[256][40];
  __shared__ int qrows[40];
  int kc = blockIdx.x, bh = blockIdx.y;
  int h = bh & 7, b = bh >> 3;
  int tid = threadIdx.x;
  int wv = tid >> 6, lane = tid & 63;
  if (tid < 40) qrows[tid] = top[bh * UU + tid];
  __syncthreads();
  for (int t = tid; t < 40 * 32; t += 256) {
    int q = t >> 5, d = t & 31;
    Qs[q][d] = Q[((size_t)(b * LL + qrows[q])) * DMM + h * EE + d];
  }
  {
    int krow = b * LL + kc * 256 + tid;
    const uint4* vp = (const uint4*)(Vbf + (size_t)krow * DMM + h * EE);
#pragma unroll
    for (int seg = 0; seg < 4; ++seg)
      *(uint4*)(&Vs[tid][seg * 8]) = vp[seg];
  }
  __syncthreads();
  {
    const float4* kp =
        (const float4*)(K + ((size_t)(b * LL + kc * 256 + tid)) * DMM + h * EE);
    float4 kr[8];
#pragma unroll
    for (int j = 0; j < 8; ++j) kr[j] = kp[j];
    const float scale = 0.17677669529663687f;
    for (int q = 0; q < 40; ++q) {
      const float4* qp = (const float4*)Qs[q];
      float s = 0.f;
#pragma unroll
      for (int j = 0; j < 8; ++j) {
        float4 qv = qp[j];
        s += qv.x * kr[j].x + qv.y * kr[j].y + qv.z * kr[j].z + qv.w * kr[j].w;
      }
      ps[q][tid] = f2b(s * scale);
    }
  }
  __syncthreads();
  int kg = lane >> 5, d = lane & 31;
  for (int qq = 0; qq < 10; ++qq) {
    int q = wv * 10 + qq;
    float mx = -1e30f;
#pragma unroll
    for (int e = 0; e < 4; ++e) mx = fmaxf(mx, bfbits(ps[q][lane + 64 * e]));
#pragma unroll
    for (int off = 32; off > 0; off >>= 1) mx = fmaxf(mx, __shfl_xor(mx, off));
    float sum = 0.f;
#pragma unroll
    for (int e = 0; e < 4; ++e) {
      int i = lane + 64 * e;
      float ev = expf(bfbits(ps[q][i]) - mx);
      sum += ev;
      ps[q][i] = f2b(ev);
    }
    sum = wave_sum(sum);
    float o = 0.f;
#pragma unroll 8
    for (int j = 0; j < 128; ++j) {
      int r = 2 * j + kg;
      o += bfbits(ps[q][r]) * bfbits(Vs[r][d]);
    }
    o += __shfl_xor(o, 32);
    size_t base = ((size_t)bh * UU + q) * 8 + kc;
    if (lane == 0) { pm[base] = mx; pl[base] = sum; }
    if (lane < 32) po[base * 32 + d] = o;
  }
}

// ---------------- fused LN1(x+t) + FFN + LN2 (+final LN, +stat zero) ----------------
__global__ __launch_bounds__(256) void enc_tail(const float* __restrict__ X,
                                                const float* __restrict__ T,
                                                const float* __restrict__ g1,
                                                const float* __restrict__ b1ln,
                                                const float* __restrict__ w1,
                                                const float* __restrict__ b1,
                                                const float* __restrict__ w2,
                                                const float* __restrict__ b2,
                                                const float* __restrict__ g2,
                                                const float* __restrict__ b2ln,
                                                float* __restrict__ Out,
                                                unsigned short* __restrict__ OutB,
                                                unsigned short* __restrict__ OutL,
                                                const float* __restrict__ fing,
                                                const float* __restrict__ finb,
                                                void* __restrict__ finOut,
                                                const int* __restrict__ flag,
                                                float* __restrict__ stpZ,
                                                float* __restrict__ stp2Z) {
  if (blockIdx.x == 0) {
    stpZ[threadIdx.x] = 0.f;
    stp2Z[threadIdx.x] = 0.f;
  }
  int wave = threadIdx.x >> 6, lane = threadIdx.x & 63;
  size_t row = (size_t)blockIdx.x * 4 + wave;
  __shared__ float xs[4][DMM];
  const float* xr = X + row * DMM;
  const float* tr = T + row * DMM;
  float v[4];
#pragma unroll
  for (int i = 0; i < 4; ++i) v[i] = xr[lane + 64 * i] + tr[lane + 64 * i];
  float s = wave_sum(v[0] + v[1] + v[2] + v[3]);
  float m = s * (1.0f / (float)DMM);
  float sq = 0.f;
#pragma unroll
  for (int i = 0; i < 4; ++i) { float d = v[i] - m; sq += d * d; }
  sq = wave_sum(sq);
  float rstd = rsqrtf(sq * (1.0f / (float)DMM) + 1e-5f);
  float xv[4];
#pragma unroll
  for (int i = 0; i < 4; ++i) {
    int d = lane + 64 * i;
    xv[i] = (v[i] - m) * rstd * g1[d] + b1ln[d];
    xs[wave][d] = xv[i];
  }
  __syncthreads();
  int f = lane & 15, qtr = lane >> 4;
  const float* w1p = w1 + f * DMM + qtr * 64;
  const float* xq = &xs[wave][qtr * 64];
  float pacc = 0.f;
#pragma unroll 8
  for (int d = 0; d < 64; ++d) pacc += xq[d] * w1p[d];
  pacc += __shfl_xor(pacc, 16);
  pacc += __shfl_xor(pacc, 32);
  float y1 = fmaxf(pacc + b1[f], 0.0f);
  float y1v[16];
#pragma unroll
  for (int ff = 0; ff < 16; ++ff) y1v[ff] = __shfl(y1, ff);
#pragma unroll
  for (int i = 0; i < 4; ++i) {
    int d = lane + 64 * i;
    const float* w2p = w2 + d * ITR;
    float a = b2[d];
#pragma unroll
    for (int ff = 0; ff < 16; ++ff) a += y1v[ff] * w2p[ff];
    v[i] = xv[i] + a;
  }
  s = wave_sum(v[0] + v[1] + v[2] + v[3]);
  m = s * (1.0f / (float)DMM);
  sq = 0.f;
#pragma unroll
  for (int i = 0; i < 4; ++i) { float d = v[i] - m; sq += d * d; }
  sq = wave_sum(sq);
  rstd = rsqrtf(sq * (1.0f / (float)DMM) + 1e-5f);
  float vv[4];
#pragma unroll
  for (int i = 0; i < 4; ++i) {
    int d = lane + 64 * i;
    float val = (v[i] - m) * rstd * g2[d] + b2ln[d];
    vv[i] = val;
    Out[row * DMM + d] = val;
    unsigned short hi = f2b(val);
    OutB[row * DMM + d] = hi;
    OutL[row * DMM + d] = f2b(val - bfbits(hi));
  }
  if (finOut) {
    s = wave_sum(vv[0] + vv[1] + vv[2] + vv[3]);
    m = s * (1.0f / (float)DMM);
    sq = 0.f;
#pragma unroll
    for (int i = 0; i < 4; ++i) { float d = vv[i] - m; sq += d * d; }
    sq = wave_sum(sq);
    rstd = rsqrtf(sq * (1.0f / (float)DMM) + 1e-5f);
    int isf32 = *flag;
#pragma unroll
    for (int i = 0; i < 4; ++i) {
      int d = lane + 64 * i;
      float val = (vv[i] - m) * rstd * fing[d] + finb[d];
      if (isf32) ((float*)finOut)[row * DMM + d] = val;
      else       ((unsigned short*)finOut)[row * DMM + d] = f2b(val);
    }
  }
}

// ---------------- bn+elu from atomic stats (+vmp zero for next layer) ----------------
__global__ __launch_bounds__(256) void bn_elu(const float* __restrict__ Y,
                                              const float* __restrict__ stp,
                                              const float* __restrict__ stp2,
                                              const float* __restrict__ g,
                                              const float* __restrict__ bb,
                                              float* __restrict__ X,
                                              unsigned short* __restrict__ XB,
                                              unsigned short* __restrict__ XL,
                                              float* __restrict__ vmpZ) {
  int gid = blockIdx.x * 256 + threadIdx.x;
  if (gid < BB * DMM) vmpZ[gid] = 0.f;
  int d = gid & 255;
  float mean = stp[d] * (1.0f / (float)ROWS);
  float var = stp2[d] * (1.0f / (float)ROWS) - mean * mean;
  float rstd = rsqrtf(var + 1e-5f);
  float v = (Y[gid] - mean) * rstd * g[d] + bb[d];
  float r = v > 0.f ? v : expm1f(v);
  X[gid] = r;
  unsigned short hi = f2b(r);
  XB[gid] = hi;
  XL[gid] = f2b(r - bfbits(hi));
}

extern "C" void kernel_launch(void* const* d_in, const int* in_sizes, int n_in,
                              void* d_out, int out_size, void* d_ws, size_t ws_size,
                              hipStream_t stream) {
  (void)in_sizes; (void)n_in; (void)out_size; (void)ws_size;

  // ---- workspace layout ----
  float* xbuf = (float*)d_ws;
  float* kb   = xbuf + NELEM;
  float* qb   = kb + NELEM;   // aliases tmp (Q dead after attn_part)
  float* tmp  = qb;
  float* Mbuf = qb + NELEM;
  float* vmp  = Mbuf + BB * HH * LL;
  float* stp  = vmp + BB * DMM;
  float* stp2 = stp + DMM;
  float* wp   = stp2 + DMM;
  const int wsz[23] = {
      NELEM,
      NLL * DMM * DMM, NLL * DMM,
      NLL * DMM * DMM, NLL * DMM,
      NLL * DMM * DMM, NLL * DMM,
      NLL * DMM * DMM, NLL * DMM,
      NLL * ITR * DMM, NLL * ITR,
      NLL * DMM * ITR, NLL * DMM,
      NLL * DMM, NLL * DMM,
      NLL * DMM, NLL * DMM,
      (NLL - 1) * DMM * DMM * 3, (NLL - 1) * DMM,
      (NLL - 1) * DMM, (NLL - 1) * DMM,
      DMM, DMM
  };
  float* fptr[23];
  fptr[0] = xbuf;
  for (int i = 1; i < 23; ++i) { fptr[i] = wp; wp += wsz[i]; }
  float* pm = wp;
  float* pl = pm + 32 * UU * 8;
  float* po = pl + 32 * UU * 8;
  unsigned short* xbf   = (unsigned short*)(po + 32 * UU * 8 * 32);
  unsigned short* xlo   = xbf + NELEM;
  unsigned short* vbf   = xlo + NELEM;
  unsigned short* wqbf  = vbf + NELEM;
  unsigned short* wkbf  = wqbf + NLL * DMM * DMM;
  unsigned short* wvbf  = wkbf + NLL * DMM * DMM;
  unsigned short* wobf  = wvbf + NLL * DMM * DMM;
  unsigned short* dcwT  = wobf + NLL * DMM * DMM;
  u64* cand = (u64*)(dcwT + (NLL - 1) * 3 * DMM * DMM);  // 256*40
  int* topb = (int*)(cand + 256 * 40);
  int* flag = topb + BB * HH * UU;
  unsigned char* mapb = (unsigned char*)(flag + 1);  // 32*2048

  // ---- probe + convert (+dcw repack, +vmp zero) ----
  probe_dtype<<<1, 256, 0, stream>>>(d_in[0], flag);
  CvtArgs ca;
  int totalBlk = 0;
  for (int i = 0; i < 23; ++i) {
    ca.src[i] = d_in[i];
    ca.dstF[i] = fptr[i];
    ca.dstB[i] = nullptr;
    ca.dstL[i] = nullptr;
    ca.n[i] = wsz[i];
    ca.blkStart[i] = totalBlk;
    totalBlk += (wsz[i] + 255) / 256;
  }
  ca.blkStart[23] = totalBlk;
  ca.dstB[0] = xbf;  ca.dstL[0] = xlo;
  ca.dstB[1] = wqbf;
  ca.dstB[3] = wkbf;
  ca.dstB[5] = wvbf;
  ca.dstB[7] = wobf;
  ca.dcwT = dcwT;
  ca.vmpZ = vmp;
  mega_cvt<<<totalBlk + 1, 256, 0, stream>>>(ca, flag);

  dim3 gqkv(ROWS / 128, DMM / 64, 3);
  dim3 g64(ROWS / 64, DMM / 64);

  for (int i = 0; i < NLL; ++i) {
    QKVArgs qa;
    qa.W[0] = wqbf + (size_t)i * DMM * DMM;
    qa.W[1] = wkbf + (size_t)i * DMM * DMM;
    qa.W[2] = wvbf + (size_t)i * DMM * DMM;
    qa.bias[0] = fptr[2] + i * DMM;
    qa.bias[1] = fptr[4] + i * DMM;
    qa.bias[2] = fptr[6] + i * DMM;
    qa.Cq = qb; qa.Ck = kb; qa.Cv = vbf;
    qa.vmp = vmp;
    gemm_qkv<<<gqkv, 256, 0, stream>>>(xbf, xlo, qa);

    uint32_t ki0, ki1, a0, a1, b0, b1;
    threefry2x32(0u, 42u, 0u, (uint32_t)i, &ki0, &ki1);
    threefry2x32(ki0, ki1, 0u, 2u, &a0, &a1);
    threefry2x32(ki0, ki1, 1u, 3u, &b0, &b1);
    (void)a0; (void)b0;

    m_kernel3<<<BB * 512, 256, 0, stream>>>(qb, kb, a1, b1, Mbuf);
    cand_topk<<<BB * HH * 8, 256, 0, stream>>>(Mbuf, cand);
    merge_topk<<<BB * HH, 256, 0, stream>>>(cand, topb, mapb);
    attn_part<<<dim3(8, BB * HH), 256, 0, stream>>>(qb, kb, vbf, topb, pm, pl, po);

    gemm_oproj<<<g64, 256, 0, stream>>>(vmp, mapb, pm, pl, po,
                                        wobf + (size_t)i * DMM * DMM,
                                        fptr[8] + i * DMM, tmp);
    bool last = (i == NLL - 1);
    enc_tail<<<ROWS / 4, 256, 0, stream>>>(
        xbuf, tmp, fptr[13] + i * DMM, fptr[14] + i * DMM,
        fptr[9] + (size_t)i * ITR * DMM, fptr[10] + i * ITR,
        fptr[11] + (size_t)i * DMM * ITR, fptr[12] + i * DMM,
        fptr[15] + i * DMM, fptr[16] + i * DMM, xbuf, xbf, xlo,
        fptr[21], fptr[22], last ? d_out : nullptr, flag, stp, stp2);

    if (!last) {
      gemm_conv<<<g64, 256, 0, stream>>>(xbf, dcwT + (size_t)i * 3 * DMM * DMM,
                                         fptr[18] + i * DMM, tmp, stp, stp2);
      bn_elu<<<NELEM / 256, 256, 0, stream>>>(tmp, stp, stp2, fptr[19] + i * DMM,
                                              fptr[20] + i * DMM, xbuf, xbf, xlo, vmp);
    }
  }
}

// Round 13
// 563.986 us; speedup vs baseline: 1.1123x; 1.0276x over previous
//
#include <hip/hip_runtime.h>
#include <stdint.h>

#define BB 4
#define LL 2048
#define DMM 256
#define HH 8
#define EE 32
#define NLL 3
#define ITR 16
#define UU 40
#define KC 16                 // split-K chunks
#define KCH 128               // keys per chunk
#define ROWS (BB*LL)          // 8192
#define NELEM (ROWS*DMM)      // 2097152

typedef __attribute__((ext_vector_type(8))) short short8;
typedef __attribute__((ext_vector_type(4))) float f32x4;
typedef unsigned long long u64;

#define GLDS16(g, l)                                                        \
  __builtin_amdgcn_global_load_lds(                                         \
      (const __attribute__((address_space(1))) uint32_t*)(g),               \
      (__attribute__((address_space(3))) uint32_t*)(l), 16, 0, 0)

// ---------------- bf16 bit helpers (RNE) ----------------
__device__ __forceinline__ float bfbits(unsigned short u) {
  return __uint_as_float(((uint32_t)u) << 16);
}
__device__ __forceinline__ unsigned short f2b(float f) {
  uint32_t u = __float_as_uint(f);
  uint32_t r = (u + 0x7FFFu + ((u >> 16) & 1u)) >> 16;
  return (unsigned short)r;
}

// ---------------- threefry2x32 (exact JAX semantics) ----------------
__host__ __device__ inline void threefry2x32(uint32_t k0, uint32_t k1,
                                             uint32_t x0, uint32_t x1,
                                             uint32_t* o0, uint32_t* o1) {
  uint32_t ks2 = k0 ^ k1 ^ 0x1BD11BDAu;
  x0 += k0; x1 += k1;
#define TFR(r) { x0 += x1; x1 = (x1 << (r)) | (x1 >> (32 - (r))); x1 ^= x0; }
  TFR(13) TFR(15) TFR(26) TFR(6)
  x0 += k1;  x1 += ks2 + 1u;
  TFR(17) TFR(29) TFR(16) TFR(24)
  x0 += ks2; x1 += k0 + 2u;
  TFR(13) TFR(15) TFR(26) TFR(6)
  x0 += k0;  x1 += k1 + 3u;
  TFR(17) TFR(29) TFR(16) TFR(24)
  x0 += k1;  x1 += ks2 + 4u;
  TFR(13) TFR(15) TFR(26) TFR(6)
  x0 += ks2; x1 += k0 + 5u;
#undef TFR
  *o0 = x0; *o1 = x1;
}

__device__ __forceinline__ float wave_sum(float v) {
#pragma unroll
  for (int off = 32; off > 0; off >>= 1) v += __shfl_xor(v, off);
  return v;
}

// ---------------- dtype probe ----------------
__global__ __launch_bounds__(256) void probe_dtype(const void* __restrict__ x,
                                                   int* __restrict__ flag) {
  __shared__ int cnt;
  if (threadIdx.x == 0) cnt = 0;
  __syncthreads();
  const unsigned short* u = (const unsigned short*)x;
  int bad = 0;
  for (int j = threadIdx.x; j < 2048; j += 256) {
    float v = bfbits(u[j]);
    float a = fabsf(v);
    bool ok = (v == 0.0f) || (a > 1e-4f && a < 100.0f);
    if (!ok) bad++;
  }
  atomicAdd(&cnt, bad);
  __syncthreads();
  if (threadIdx.x == 0) *flag = (cnt > 100) ? 1 : 0;
}

// ---------------- mega convert (+hi/lo splits, +dcw repack, +vmp zero) ----------------
struct CvtArgs {
  const void* src[23];
  float* dstF[23];
  unsigned short* dstB[23];
  unsigned short* dstL[23];
  int n[23];
  int blkStart[24];
  unsigned short* dcwT;
  float* vmpZ;     // zero BB*DMM floats
};
__global__ __launch_bounds__(256) void mega_cvt(CvtArgs a, const int* __restrict__ flag) {
  int bid = blockIdx.x;
  if (bid == a.blkStart[23]) {
    for (int t = threadIdx.x; t < BB * DMM; t += 256) a.vmpZ[t] = 0.f;
    return;
  }
  int i = 0;
  while (i < 22 && bid >= a.blkStart[i + 1]) ++i;
  int e = (bid - a.blkStart[i]) * 256 + (int)threadIdx.x;
  if (e >= a.n[i]) return;
  float v; unsigned short rw;
  if (*flag) { v = ((const float*)a.src[i])[e]; rw = f2b(v); }
  else       { rw = ((const unsigned short*)a.src[i])[e]; v = bfbits(rw); }
  a.dstF[i][e] = v;
  if (a.dstB[i]) a.dstB[i][e] = rw;
  if (a.dstL[i]) a.dstL[i][e] = f2b(v - bfbits(rw));
  if (i == 17) {  // dcw: [ly][n][k][t] -> [ly][t][n][k] bf16
    int ly = e / 196608;
    int r = e - ly * 196608;
    int n = r / 768;
    int rem = r - n * 768;
    int k = rem / 3, t = rem - k * 3;
    a.dcwT[ly * 196608 + t * 65536 + n * 256 + k] = rw;
  }
}

// ---------------- QKV MFMA GEMM: z=0:Q 1:K (hi/lo 2-pass, f32 out) 2:V (bf16 out + vmean) --
struct QKVArgs {
  const unsigned short* W[3];
  const float* bias[3];
  float* Cq;
  float* Ck;
  unsigned short* Cv;
  float* vmp;
};
__global__ __launch_bounds__(256) void gemm_qkv(const unsigned short* __restrict__ Ahi,
                                                const unsigned short* __restrict__ Alo,
                                                QKVArgs qa) {
  __shared__ __attribute__((aligned(16))) unsigned short AsH[128][32];
  __shared__ __attribute__((aligned(16))) unsigned short AsL[128][32];
  __shared__ __attribute__((aligned(16))) unsigned short Bs[64][32];
  int z = blockIdx.z;
  const unsigned short* W = qa.W[z];
  const float* bias = qa.bias[z];
  bool twoPass = (z < 2);
  int bm = blockIdx.x * 128, bn = blockIdx.y * 64;
  int tid = threadIdx.x;
  int wv = tid >> 6, lane = tid & 63;
  int wm = wv >> 1, wn = wv & 1;
  int l15 = lane & 15, quad = lane >> 4;
  int lrow = lane >> 2, lseg = lane & 3;
  f32x4 acc[4][2];
#pragma unroll
  for (int i = 0; i < 4; ++i)
#pragma unroll
    for (int j = 0; j < 2; ++j) acc[i][j] = (f32x4){0.f, 0.f, 0.f, 0.f};
  for (int k0 = 0; k0 < 256; k0 += 32) {
    __syncthreads();
#pragma unroll
    for (int s = 0; s < 2; ++s) {
      int brow = (wv + s * 4) * 16;
      size_t goff = (size_t)(bm + brow + lrow) * 256 + k0 + lseg * 8;
      GLDS16(Ahi + goff, &AsH[brow][0]);
      if (twoPass) GLDS16(Alo + goff, &AsL[brow][0]);
    }
    {
      int brow = wv * 16;
      GLDS16(W + (size_t)(bn + brow + lrow) * 256 + k0 + lseg * 8, &Bs[brow][0]);
    }
    __syncthreads();
    short8 ah[4], bfr[2];
#pragma unroll
    for (int mt = 0; mt < 4; ++mt)
      ah[mt] = *(const short8*)(&AsH[wm * 64 + mt * 16 + l15][quad * 8]);
#pragma unroll
    for (int nt = 0; nt < 2; ++nt)
      bfr[nt] = *(const short8*)(&Bs[wn * 32 + nt * 16 + l15][quad * 8]);
#pragma unroll
    for (int mt = 0; mt < 4; ++mt)
#pragma unroll
      for (int nt = 0; nt < 2; ++nt)
        acc[mt][nt] = __builtin_amdgcn_mfma_f32_16x16x32_bf16(ah[mt], bfr[nt],
                                                              acc[mt][nt], 0, 0, 0);
    if (twoPass) {
      short8 al[4];
#pragma unroll
      for (int mt = 0; mt < 4; ++mt)
        al[mt] = *(const short8*)(&AsL[wm * 64 + mt * 16 + l15][quad * 8]);
#pragma unroll
      for (int mt = 0; mt < 4; ++mt)
#pragma unroll
        for (int nt = 0; nt < 2; ++nt)
          acc[mt][nt] = __builtin_amdgcn_mfma_f32_16x16x32_bf16(al[mt], bfr[nt],
                                                                acc[mt][nt], 0, 0, 0);
    }
  }
  float* C = (z == 0) ? qa.Cq : qa.Ck;
#pragma unroll
  for (int nt = 0; nt < 2; ++nt) {
    int n = bn + wn * 32 + nt * 16 + l15;
    float bv = bias[n];
    float csum = 0.f;
#pragma unroll
    for (int mt = 0; mt < 4; ++mt)
#pragma unroll
      for (int r = 0; r < 4; ++r) {
        int m = bm + wm * 64 + mt * 16 + quad * 4 + r;
        float val = acc[mt][nt][r] + bv;
        if (z < 2) {
          C[(size_t)m * 256 + n] = val;
        } else {
          qa.Cv[(size_t)m * 256 + n] = f2b(val);
          csum += val;
        }
      }
    if (z == 2) {
      csum += __shfl_xor(csum, 16);
      csum += __shfl_xor(csum, 32);
      if (quad == 0) {
        int b = bm >> 11;
        atomicAdd(&qa.vmp[b * DMM + n], csum);
      }
    }
  }
}

// ---------------- O-proj GEMM with on-the-fly ctx A-tiles (KC=16 merge) ----------------
__global__ __launch_bounds__(256) void gemm_oproj(const float* __restrict__ vmp,
                                                  const unsigned char* __restrict__ mapb,
                                                  const float* __restrict__ pm,
                                                  const float* __restrict__ pl,
                                                  const float* __restrict__ po,
                                                  const unsigned short* __restrict__ W,
                                                  const float* __restrict__ bias,
                                                  float* __restrict__ C) {
  __shared__ __attribute__((aligned(16))) unsigned short As[64][32];
  __shared__ __attribute__((aligned(16))) unsigned short Bs[64][32];
  int bm = blockIdx.x * 64, bn = blockIdx.y * 64;
  int tid = threadIdx.x;
  int wv = tid >> 6, lane = tid & 63;
  int wm = wv >> 1, wn = wv & 1;
  int l15 = lane & 15, quad = lane >> 4;
  int lrow = lane >> 2, lseg = lane & 3;
  int arow = tid >> 2, adg = tid & 3;
  int b = bm >> 11, l0 = bm & 2047;
  const float invL = 1.0f / (float)LL;
  f32x4 acc[2][2];
#pragma unroll
  for (int i = 0; i < 2; ++i)
#pragma unroll
    for (int j = 0; j < 2; ++j) acc[i][j] = (f32x4){0.f, 0.f, 0.f, 0.f};
  for (int k0 = 0; k0 < 256; k0 += 32) {
    int h = k0 >> 5;
    int bh = b * HH + h;
    __syncthreads();
    {
      int l = l0 + arow;
      int q = (int)mapb[bh * 2048 + l];
      unsigned short outv[8];
      if (q) {
        size_t base = ((size_t)bh * UU + (q - 1)) * KC;
        float Mx = -1e30f;
#pragma unroll
        for (int kc = 0; kc < KC; ++kc) Mx = fmaxf(Mx, pm[base + kc]);
        float Ls = 0.f;
        float sc[KC];
#pragma unroll
        for (int kc = 0; kc < KC; ++kc) {
          sc[kc] = expf(pm[base + kc] - Mx);
          Ls += pl[base + kc] * sc[kc];
        }
        float inv = 1.0f / Ls;
#pragma unroll
        for (int j = 0; j < 8; ++j) {
          int dl = adg * 8 + j;
          float o = 0.f;
#pragma unroll
          for (int kc = 0; kc < KC; ++kc) o += po[(base + kc) * 32 + dl] * sc[kc];
          outv[j] = f2b(o * inv);
        }
      } else {
        const float* vp = vmp + b * DMM + h * EE + adg * 8;
#pragma unroll
        for (int j = 0; j < 8; ++j) outv[j] = f2b(vp[j] * invL);
      }
      *(uint4*)(&As[arow][adg * 8]) = *(const uint4*)outv;
    }
    {
      int brow = wv * 16;
      GLDS16(W + (size_t)(bn + brow + lrow) * 256 + k0 + lseg * 8, &Bs[brow][0]);
    }
    __syncthreads();
    short8 af[2], bfr[2];
#pragma unroll
    for (int mt = 0; mt < 2; ++mt)
      af[mt] = *(const short8*)(&As[wm * 32 + mt * 16 + l15][quad * 8]);
#pragma unroll
    for (int nt = 0; nt < 2; ++nt)
      bfr[nt] = *(const short8*)(&Bs[wn * 32 + nt * 16 + l15][quad * 8]);
#pragma unroll
    for (int mt = 0; mt < 2; ++mt)
#pragma unroll
      for (int nt = 0; nt < 2; ++nt)
        acc[mt][nt] = __builtin_amdgcn_mfma_f32_16x16x32_bf16(af[mt], bfr[nt],
                                                              acc[mt][nt], 0, 0, 0);
  }
#pragma unroll
  for (int nt = 0; nt < 2; ++nt) {
    int n = bn + wn * 32 + nt * 16 + l15;
    float bv = bias[n];
#pragma unroll
    for (int mt = 0; mt < 2; ++mt)
#pragma unroll
      for (int r = 0; r < 4; ++r) {
        int m = bm + wm * 32 + mt * 16 + quad * 4 + r;
        C[(size_t)m * 256 + n] = acc[mt][nt][r] + bv;
      }
  }
}

// ---------------- conv GEMM: A window staged once per k0, 3 taps from LDS ----------------
__global__ __launch_bounds__(256) void gemm_conv(const unsigned short* __restrict__ A,
                                                 const unsigned short* __restrict__ W,
                                                 const float* __restrict__ bias,
                                                 float* __restrict__ C,
                                                 float* __restrict__ stp,
                                                 float* __restrict__ stp2) {
  __shared__ __attribute__((aligned(16))) unsigned short As[80][32];
  __shared__ __attribute__((aligned(16))) unsigned short Bs[192][32];
  int bm = blockIdx.x * 64, bn = blockIdx.y * 64;
  int tid = threadIdx.x;
  int wv = tid >> 6, lane = tid & 63;
  int wm = wv >> 1, wn = wv & 1;
  int l15 = lane & 15, quad = lane >> 4;
  int lrow = lane >> 2, lseg = lane & 3;
  int bbase = bm & ~2047, l0 = bm & 2047;
  f32x4 acc[2][2];
#pragma unroll
  for (int i = 0; i < 2; ++i)
#pragma unroll
    for (int j = 0; j < 2; ++j) acc[i][j] = (f32x4){0.f, 0.f, 0.f, 0.f};
  for (int k0 = 0; k0 < 256; k0 += 32) {
    __syncthreads();
    for (int c = wv; c < 5; c += 4) {
      int i0 = c * 16;
      int l = (l0 - 1 + i0 + lrow + 2048) & 2047;
      GLDS16(A + (size_t)(bbase | l) * 256 + k0 + lseg * 8, &As[i0][0]);
    }
    for (int c = wv; c < 12; c += 4) {
      int i0 = c * 16;
      int tap = c >> 2, brow = (c & 3) * 16;
      GLDS16(W + (size_t)tap * 65536 + (size_t)(bn + brow + lrow) * 256 + k0 + lseg * 8,
             &Bs[i0][0]);
    }
    __syncthreads();
#pragma unroll
    for (int tap = 0; tap < 3; ++tap) {
      short8 af[2], bfr[2];
#pragma unroll
      for (int mt = 0; mt < 2; ++mt)
        af[mt] = *(const short8*)(&As[wm * 32 + mt * 16 + l15 + tap][quad * 8]);
#pragma unroll
      for (int nt = 0; nt < 2; ++nt)
        bfr[nt] = *(const short8*)(&Bs[tap * 64 + wn * 32 + nt * 16 + l15][quad * 8]);
#pragma unroll
      for (int mt = 0; mt < 2; ++mt)
#pragma unroll
        for (int nt = 0; nt < 2; ++nt)
          acc[mt][nt] = __builtin_amdgcn_mfma_f32_16x16x32_bf16(af[mt], bfr[nt],
                                                                acc[mt][nt], 0, 0, 0);
    }
  }
#pragma unroll
  for (int nt = 0; nt < 2; ++nt) {
    int n = bn + wn * 32 + nt * 16 + l15;
    float bv = bias[n];
    float s = 0.f, s2 = 0.f;
#pragma unroll
    for (int mt = 0; mt < 2; ++mt)
#pragma unroll
      for (int r = 0; r < 4; ++r) {
        int m = bm + wm * 32 + mt * 16 + quad * 4 + r;
        float val = acc[mt][nt][r] + bv;
        C[(size_t)m * 256 + n] = val;
        s += val;
        s2 += val * val;
      }
    s  += __shfl_xor(s, 16);   s  += __shfl_xor(s, 32);
    s2 += __shfl_xor(s2, 16);  s2 += __shfl_xor(s2, 32);
    if (quad == 0) {
      atomicAdd(&stp[n], s);
      atomicAdd(&stp2[n], s2);
    }
  }
}

// ---------------- M scores: wave per (b,l), inline threefry ----------------
__global__ __launch_bounds__(256) void m_kernel3(const float* __restrict__ Q,
                                                 const float* __restrict__ K,
                                                 uint32_t k20, uint32_t k21,
                                                 float* __restrict__ M) {
  int blk = blockIdx.x;
  int b = blk >> 9, lc = blk & 511;
  int wave = threadIdx.x >> 6, lane = threadIdx.x & 63;
  int l = lc * 4 + wave;
  int myidx = 0;
  if (lane < UU) {
    int j = l * UU + lane;
    uint32_t o0, o1;
    const int half = (LL * UU) / 2;  // 40960
    if (j < half) {
      threefry2x32(k20, k21, (uint32_t)j, (uint32_t)(j + half), &o0, &o1);
      myidx = (int)(o0 & (LL - 1));
    } else {
      threefry2x32(k20, k21, (uint32_t)(j - half), (uint32_t)j, &o0, &o1);
      myidx = (int)(o1 & (LL - 1));
    }
  }
  float4 q4 = *(const float4*)(Q + ((size_t)(b * LL + l)) * DMM + lane * 4);
  const float* Kb = K + (size_t)b * LL * DMM;
  float mx = -1e30f, sm = 0.f;
#pragma unroll 4
  for (int u = 0; u < UU; ++u) {
    int kidx = __shfl(myidx, u);
    float4 k4 = *(const float4*)(Kb + (size_t)kidx * DMM + lane * 4);
    float s = q4.x * k4.x + q4.y * k4.y + q4.z * k4.z + q4.w * k4.w;
    s += __shfl_xor(s, 1);
    s += __shfl_xor(s, 2);
    s += __shfl_xor(s, 4);
    mx = fmaxf(mx, s);
    sm += s;
  }
  if ((lane & 7) == 0) {
    int h = lane >> 3;
    M[((size_t)(b * HH + h)) * LL + l] = mx - sm * (1.0f / (float)LL);
  }
}

// ---------------- top-k stage A: per-256-chunk bitonic, emit top-40 ----------------
__global__ __launch_bounds__(256) void cand_topk(const float* __restrict__ M,
                                                 u64* __restrict__ cand) {
  __shared__ u64 a[256];
  int bh = blockIdx.x >> 3, c = blockIdx.x & 7;
  int tid = threadIdx.x;
  int l = c * 256 + tid;
  float v = M[(size_t)bh * LL + l];
  uint32_t bits = __float_as_uint(v);
  uint32_t kv = (bits & 0x80000000u) ? ~bits : (bits | 0x80000000u);
  a[tid] = ((u64)kv << 32) | (uint32_t)(2047 - l);
  __syncthreads();
  for (int k = 2; k <= 256; k <<= 1)
    for (int j = k >> 1; j > 0; j >>= 1) {
      int ixj = tid ^ j;
      if (ixj > tid) {
        bool up = ((tid & k) == 0);
        u64 x = a[tid], y = a[ixj];
        if ((x > y) == up) { a[tid] = y; a[ixj] = x; }
      }
      __syncthreads();
    }
  if (tid >= 216) cand[(size_t)blockIdx.x * 40 + (tid - 216)] = a[tid];
}

// ---------------- top-k stage B: merge 320 candidates (+selection map) ----------------
__global__ __launch_bounds__(256) void merge_topk(const u64* __restrict__ cand,
                                                  int* __restrict__ top,
                                                  unsigned char* __restrict__ mapb) {
  __shared__ u64 a[512];
  int bh = blockIdx.x;
  int tid = threadIdx.x;
  for (int t = tid; t < 2048; t += 256) mapb[bh * 2048 + t] = 0;
  for (int t = tid; t < 512; t += 256)
    a[t] = (t < 320) ? cand[(size_t)bh * 320 + t] : 0ULL;
  __syncthreads();
  for (int k = 2; k <= 512; k <<= 1)
    for (int j = k >> 1; j > 0; j >>= 1) {
      for (int t = tid; t < 512; t += 256) {
        int ixj = t ^ j;
        if (ixj > t) {
          bool up = ((t & k) == 0);
          u64 x = a[t], y = a[ixj];
          if ((x > y) == up) { a[t] = y; a[ixj] = x; }
        }
      }
      __syncthreads();
    }
  if (tid < UU) {
    u64 key = a[511 - tid];
    int l = 2047 - (int)(uint32_t)(key & 0xFFFFFFFFu);
    top[bh * UU + tid] = l;
    mapb[bh * 2048 + l] = (unsigned char)(tid + 1);
  }
}

// ---------------- split-K flash attention: partials (KC=16, 128 keys/block) ----------------
__global__ __launch_bounds__(256) void attn_part(const float* __restrict__ Q,
                                                 const float* __restrict__ K,
                                                 const unsigned short* __restrict__ Vbf,
                                                 const int* __restrict__ top,
                                                 float* __restrict__ pm,
                                                 float* __restrict__ pl,
                                                 float* __restrict__ po) {
  __shared__ float Qs[40][32];
  __shared__ unsigned short ps[40][KCH];
  __shared__ unsigned short Vs[KCH][40];
  __shared__ int qrows[40];
  int kc = blockIdx.x, bh = blockIdx.y;
  int h = bh & 7, b = bh >> 3;
  int tid = threadIdx.x;
  int wv = tid >> 6, lane = tid & 63;
  if (tid < 40) qrows[tid] = top[bh * UU + tid];
  __syncthreads();
  for (int t = tid; t < 40 * 32; t += 256) {
    int q = t >> 5, d = t & 31;
    Qs[q][d] = Q[((size_t)(b * LL + qrows[q])) * DMM + h * EE + d];
  }
  {
    int row = tid >> 1, half = tid & 1;
    const unsigned short* vsrc =
        Vbf + (size_t)(b * LL + kc * KCH + row) * DMM + h * EE + half * 16;
    *(uint4*)(&Vs[row][half * 16]) = *(const uint4*)vsrc;
    *(uint4*)(&Vs[row][half * 16 + 8]) = *(const uint4*)(vsrc + 8);
  }
  __syncthreads();
  {
    int k = tid & (KCH - 1), qh = tid >> 7;  // 2 threads/key, 20 queries each
    const float4* kp =
        (const float4*)(K + ((size_t)(b * LL + kc * KCH + k)) * DMM + h * EE);
    float4 kr[8];
#pragma unroll
    for (int j = 0; j < 8; ++j) kr[j] = kp[j];
    const float scale = 0.17677669529663687f;
    for (int q = qh * 20; q < qh * 20 + 20; ++q) {
      const float4* qp = (const float4*)Qs[q];
      float s = 0.f;
#pragma unroll
      for (int j = 0; j < 8; ++j) {
        float4 qv = qp[j];
        s += qv.x * kr[j].x + qv.y * kr[j].y + qv.z * kr[j].z + qv.w * kr[j].w;
      }
      ps[q][k] = f2b(s * scale);
    }
  }
  __syncthreads();
  int kg = lane >> 5, d = lane & 31;
  for (int qq = 0; qq < 10; ++qq) {
    int q = wv * 10 + qq;
    float mx = fmaxf(bfbits(ps[q][lane]), bfbits(ps[q][lane + 64]));
#pragma unroll
    for (int off = 32; off > 0; off >>= 1) mx = fmaxf(mx, __shfl_xor(mx, off));
    float e0 = expf(bfbits(ps[q][lane]) - mx);
    float e1 = expf(bfbits(ps[q][lane + 64]) - mx);
    ps[q][lane] = f2b(e0);
    ps[q][lane + 64] = f2b(e1);
    float sum = wave_sum(e0 + e1);
    float o = 0.f;
#pragma unroll 8
    for (int j = 0; j < KCH / 2; ++j) {
      int r = 2 * j + kg;
      o += bfbits(ps[q][r]) * bfbits(Vs[r][d]);
    }
    o += __shfl_xor(o, 32);
    size_t base = ((size_t)bh * UU + q) * KC + kc;
    if (lane == 0) { pm[base] = mx; pl[base] = sum; }
    if (lane < 32) po[base * 32 + d] = o;
  }
}

// ---------------- fused LN1(x+t) + FFN + LN2 (+final LN, +stat zero) ----------------
__global__ __launch_bounds__(256) void enc_tail(const float* __restrict__ X,
                                                const float* __restrict__ T,
                                                const float* __restrict__ g1,
                                                const float* __restrict__ b1ln,
                                                const float* __restrict__ w1,
                                                const float* __restrict__ b1,
                                                const float* __restrict__ w2,
                                                const float* __restrict__ b2,
                                                const float* __restrict__ g2,
                                                const float* __restrict__ b2ln,
                                                float* __restrict__ Out,
                                                unsigned short* __restrict__ OutB,
                                                unsigned short* __restrict__ OutL,
                                                const float* __restrict__ fing,
                                                const float* __restrict__ finb,
                                                void* __restrict__ finOut,
                                                const int* __restrict__ flag,
                                                float* __restrict__ stpZ,
                                                float* __restrict__ stp2Z) {
  if (blockIdx.x == 0) {
    stpZ[threadIdx.x] = 0.f;
    stp2Z[threadIdx.x] = 0.f;
  }
  int wave = threadIdx.x >> 6, lane = threadIdx.x & 63;
  size_t row = (size_t)blockIdx.x * 4 + wave;
  __shared__ float xs[4][DMM];
  const float* xr = X + row * DMM;
  const float* tr = T + row * DMM;
  float v[4];
#pragma unroll
  for (int i = 0; i < 4; ++i) v[i] = xr[lane + 64 * i] + tr[lane + 64 * i];
  float s = wave_sum(v[0] + v[1] + v[2] + v[3]);
  float m = s * (1.0f / (float)DMM);
  float sq = 0.f;
#pragma unroll
  for (int i = 0; i < 4; ++i) { float d = v[i] - m; sq += d * d; }
  sq = wave_sum(sq);
  float rstd = rsqrtf(sq * (1.0f / (float)DMM) + 1e-5f);
  float xv[4];
#pragma unroll
  for (int i = 0; i < 4; ++i) {
    int d = lane + 64 * i;
    xv[i] = (v[i] - m) * rstd * g1[d] + b1ln[d];
    xs[wave][d] = xv[i];
  }
  __syncthreads();
  int f = lane & 15, qtr = lane >> 4;
  const float* w1p = w1 + f * DMM + qtr * 64;
  const float* xq = &xs[wave][qtr * 64];
  float pacc = 0.f;
#pragma unroll 8
  for (int d = 0; d < 64; ++d) pacc += xq[d] * w1p[d];
  pacc += __shfl_xor(pacc, 16);
  pacc += __shfl_xor(pacc, 32);
  float y1 = fmaxf(pacc + b1[f], 0.0f);
  float y1v[16];
#pragma unroll
  for (int ff = 0; ff < 16; ++ff) y1v[ff] = __shfl(y1, ff);
#pragma unroll
  for (int i = 0; i < 4; ++i) {
    int d = lane + 64 * i;
    const float* w2p = w2 + d * ITR;
    float a = b2[d];
#pragma unroll
    for (int ff = 0; ff < 16; ++ff) a += y1v[ff] * w2p[ff];
    v[i] = xv[i] + a;
  }
  s = wave_sum(v[0] + v[1] + v[2] + v[3]);
  m = s * (1.0f / (float)DMM);
  sq = 0.f;
#pragma unroll
  for (int i = 0; i < 4; ++i) { float d = v[i] - m; sq += d * d; }
  sq = wave_sum(sq);
  rstd = rsqrtf(sq * (1.0f / (float)DMM) + 1e-5f);
  float vv[4];
#pragma unroll
  for (int i = 0; i < 4; ++i) {
    int d = lane + 64 * i;
    float val = (v[i] - m) * rstd * g2[d] + b2ln[d];
    vv[i] = val;
    Out[row * DMM + d] = val;
    unsigned short hi = f2b(val);
    OutB[row * DMM + d] = hi;
    OutL[row * DMM + d] = f2b(val - bfbits(hi));
  }
  if (finOut) {
    s = wave_sum(vv[0] + vv[1] + vv[2] + vv[3]);
    m = s * (1.0f / (float)DMM);
    sq = 0.f;
#pragma unroll
    for (int i = 0; i < 4; ++i) { float d = vv[i] - m; sq += d * d; }
    sq = wave_sum(sq);
    rstd = rsqrtf(sq * (1.0f / (float)DMM) + 1e-5f);
    int isf32 = *flag;
#pragma unroll
    for (int i = 0; i < 4; ++i) {
      int d = lane + 64 * i;
      float val = (vv[i] - m) * rstd * fing[d] + finb[d];
      if (isf32) ((float*)finOut)[row * DMM + d] = val;
      else       ((unsigned short*)finOut)[row * DMM + d] = f2b(val);
    }
  }
}

// ---------------- bn+elu from atomic stats (+vmp zero for next layer) ----------------
__global__ __launch_bounds__(256) void bn_elu(const float* __restrict__ Y,
                                              const float* __restrict__ stp,
                                              const float* __restrict__ stp2,
                                              const float* __restrict__ g,
                                              const float* __restrict__ bb,
                                              float* __restrict__ X,
                                              unsigned short* __restrict__ XB,
                                              unsigned short* __restrict__ XL,
                                              float* __restrict__ vmpZ) {
  int gid = blockIdx.x * 256 + threadIdx.x;
  if (gid < BB * DMM) vmpZ[gid] = 0.f;
  int d = gid & 255;
  float mean = stp[d] * (1.0f / (float)ROWS);
  float var = stp2[d] * (1.0f / (float)ROWS) - mean * mean;
  float rstd = rsqrtf(var + 1e-5f);
  float v = (Y[gid] - mean) * rstd * g[d] + bb[d];
  float r = v > 0.f ? v : expm1f(v);
  X[gid] = r;
  unsigned short hi = f2b(r);
  XB[gid] = hi;
  XL[gid] = f2b(r - bfbits(hi));
}

extern "C" void kernel_launch(void* const* d_in, const int* in_sizes, int n_in,
                              void* d_out, int out_size, void* d_ws, size_t ws_size,
                              hipStream_t stream) {
  (void)in_sizes; (void)n_in; (void)out_size; (void)ws_size;

  // ---- workspace layout ----
  float* xbuf = (float*)d_ws;
  float* kb   = xbuf + NELEM;
  float* qb   = kb + NELEM;   // aliases tmp (Q dead after attn_part)
  float* tmp  = qb;
  float* Mbuf = qb + NELEM;
  float* vmp  = Mbuf + BB * HH * LL;
  float* stp  = vmp + BB * DMM;
  float* stp2 = stp + DMM;
  float* wp   = stp2 + DMM;
  const int wsz[23] = {
      NELEM,
      NLL * DMM * DMM, NLL * DMM,
      NLL * DMM * DMM, NLL * DMM,
      NLL * DMM * DMM, NLL * DMM,
      NLL * DMM * DMM, NLL * DMM,
      NLL * ITR * DMM, NLL * ITR,
      NLL * DMM * ITR, NLL * DMM,
      NLL * DMM, NLL * DMM,
      NLL * DMM, NLL * DMM,
      (NLL - 1) * DMM * DMM * 3, (NLL - 1) * DMM,
      (NLL - 1) * DMM, (NLL - 1) * DMM,
      DMM, DMM
  };
  float* fptr[23];
  fptr[0] = xbuf;
  for (int i = 1; i < 23; ++i) { fptr[i] = wp; wp += wsz[i]; }
  float* pm = wp;
  float* pl = pm + 32 * UU * KC;
  float* po = pl + 32 * UU * KC;
  unsigned short* xbf   = (unsigned short*)(po + 32 * UU * KC * 32);
  unsigned short* xlo   = xbf + NELEM;
  unsigned short* vbf   = xlo + NELEM;
  unsigned short* wqbf  = vbf + NELEM;
  unsigned short* wkbf  = wqbf + NLL * DMM * DMM;
  unsigned short* wvbf  = wkbf + NLL * DMM * DMM;
  unsigned short* wobf  = wvbf + NLL * DMM * DMM;
  unsigned short* dcwT  = wobf + NLL * DMM * DMM;
  u64* cand = (u64*)(dcwT + (NLL - 1) * 3 * DMM * DMM);  // 256*40
  int* topb = (int*)(cand + 256 * 40);
  int* flag = topb + BB * HH * UU;
  unsigned char* mapb = (unsigned char*)(flag + 1);  // 32*2048

  // ---- probe + convert (+dcw repack, +vmp zero) ----
  probe_dtype<<<1, 256, 0, stream>>>(d_in[0], flag);
  CvtArgs ca;
  int totalBlk = 0;
  for (int i = 0; i < 23; ++i) {
    ca.src[i] = d_in[i];
    ca.dstF[i] = fptr[i];
    ca.dstB[i] = nullptr;
    ca.dstL[i] = nullptr;
    ca.n[i] = wsz[i];
    ca.blkStart[i] = totalBlk;
    totalBlk += (wsz[i] + 255) / 256;
  }
  ca.blkStart[23] = totalBlk;
  ca.dstB[0] = xbf;  ca.dstL[0] = xlo;
  ca.dstB[1] = wqbf;
  ca.dstB[3] = wkbf;
  ca.dstB[5] = wvbf;
  ca.dstB[7] = wobf;
  ca.dcwT = dcwT;
  ca.vmpZ = vmp;
  mega_cvt<<<totalBlk + 1, 256, 0, stream>>>(ca, flag);

  dim3 gqkv(ROWS / 128, DMM / 64, 3);
  dim3 g64(ROWS / 64, DMM / 64);

  for (int i = 0; i < NLL; ++i) {
    QKVArgs qa;
    qa.W[0] = wqbf + (size_t)i * DMM * DMM;
    qa.W[1] = wkbf + (size_t)i * DMM * DMM;
    qa.W[2] = wvbf + (size_t)i * DMM * DMM;
    qa.bias[0] = fptr[2] + i * DMM;
    qa.bias[1] = fptr[4] + i * DMM;
    qa.bias[2] = fptr[6] + i * DMM;
    qa.Cq = qb; qa.Ck = kb; qa.Cv = vbf;
    qa.vmp = vmp;
    gemm_qkv<<<gqkv, 256, 0, stream>>>(xbf, xlo, qa);

    uint32_t ki0, ki1, a0, a1, b0, b1;
    threefry2x32(0u, 42u, 0u, (uint32_t)i, &ki0, &ki1);
    threefry2x32(ki0, ki1, 0u, 2u, &a0, &a1);
    threefry2x32(ki0, ki1, 1u, 3u, &b0, &b1);
    (void)a0; (void)b0;

    m_kernel3<<<BB * 512, 256, 0, stream>>>(qb, kb, a1, b1, Mbuf);
    cand_topk<<<BB * HH * 8, 256, 0, stream>>>(Mbuf, cand);
    merge_topk<<<BB * HH, 256, 0, stream>>>(cand, topb, mapb);
    attn_part<<<dim3(KC, BB * HH), 256, 0, stream>>>(qb, kb, vbf, topb, pm, pl, po);

    gemm_oproj<<<g64, 256, 0, stream>>>(vmp, mapb, pm, pl, po,
                                        wobf + (size_t)i * DMM * DMM,
                                        fptr[8] + i * DMM, tmp);
    bool last = (i == NLL - 1);
    enc_tail<<<ROWS / 4, 256, 0, stream>>>(
        xbuf, tmp, fptr[13] + i * DMM, fptr[14] + i * DMM,
        fptr[9] + (size_t)i * ITR * DMM, fptr[10] + i * ITR,
        fptr[11] + (size_t)i * DMM * ITR, fptr[12] + i * DMM,
        fptr[15] + i * DMM, fptr[16] + i * DMM, xbuf, xbf, xlo,
        fptr[21], fptr[22], last ? d_out : nullptr, flag, stp, stp2);

    if (!last) {
      gemm_conv<<<g64, 256, 0, stream>>>(xbf, dcwT + (size_t)i * 3 * DMM * DMM,
                                         fptr[18] + i * DMM, tmp, stp, stp2);
      bn_elu<<<NELEM / 256, 256, 0, stream>>>(tmp, stp, stp2, fptr[19] + i * DMM,
                                              fptr[20] + i * DMM, xbuf, xbf, xlo, vmp);
    }
  }
}